// Round 6
// baseline (253.462 us; speedup 1.0000x reference)
//
#include <hip/hip_runtime.h>
#include <math.h>

#define BB  2
#define TT  2048
#define SSQ 2048
#define DD  1024
#define HH  16
#define DKK 64
#define MM  (BB*TT)      // 4096 rows of activations
#define NN  (HH*DKK)     // 1024 proj width

typedef __attribute__((ext_vector_type(8))) short short8;
typedef __attribute__((ext_vector_type(4))) float f32x4;
typedef __attribute__((ext_vector_type(2))) unsigned int uint2v;
typedef __attribute__((ext_vector_type(4))) unsigned int u32x4;

__device__ __forceinline__ short f2bf(float x) {
    unsigned u = __builtin_bit_cast(unsigned, x);
    unsigned r = (u + 0x7FFFu + ((u >> 16) & 1u)) >> 16;
    return (short)r;
}

// pack two f32 into a bf16x2 word by truncation
__device__ __forceinline__ unsigned pk2(float lo, float hi) {
    return (__builtin_bit_cast(unsigned, hi) & 0xFFFF0000u) |
           (__builtin_bit_cast(unsigned, lo) >> 16);
}

// 8x f32 -> 8x bf16 via v_cvt_pk_bf16_f32 (RNE), 4 instrs
__device__ __forceinline__ short8 cvt8(f32x4 x, f32x4 y) {
    unsigned r0, r1, r2, r3;
    asm("v_cvt_pk_bf16_f32 %0, %1, %2" : "=v"(r0) : "v"(x[0]), "v"(x[1]));
    asm("v_cvt_pk_bf16_f32 %0, %1, %2" : "=v"(r1) : "v"(x[2]), "v"(x[3]));
    asm("v_cvt_pk_bf16_f32 %0, %1, %2" : "=v"(r2) : "v"(y[0]), "v"(y[1]));
    asm("v_cvt_pk_bf16_f32 %0, %1, %2" : "=v"(r3) : "v"(y[2]), "v"(y[3]));
    u32x4 r;
    r[0] = r0; r[1] = r1; r[2] = r2; r[3] = r3;
    return __builtin_bit_cast(short8, r);
}

__device__ __forceinline__ void glds16(const void* g, void* l) {
    __builtin_amdgcn_global_load_lds(
        (const __attribute__((address_space(1))) void*)g,
        (__attribute__((address_space(3))) void*)l, 16, 0, 0);
}

// ---------------------------------------------------------------------------
// Weight transpose+convert: fp32 [K=1024][N=1024] -> bf16 [N][K].
// grid (16,16,4): z picks which weight.
// ---------------------------------------------------------------------------
__global__ __launch_bounds__(256)
void wtrans(const float* __restrict__ w0, const float* __restrict__ w1,
            const float* __restrict__ w2, const float* __restrict__ w3,
            short* __restrict__ t0, short* __restrict__ t1,
            short* __restrict__ t2, short* __restrict__ t3)
{
    __shared__ float Ls[64][65];
    int z = blockIdx.z;
    const float* in = (z == 0) ? w0 : (z == 1) ? w1 : (z == 2) ? w2 : w3;
    short* out = (z == 0) ? t0 : (z == 1) ? t1 : (z == 2) ? t2 : t3;
    const int r0 = blockIdx.y * 64, c0 = blockIdx.x * 64;
    const int t = threadIdx.x;
    const int r = t >> 2, c4 = t & 3;

    const float* src = in + (size_t)(r0 + r) * DD + c0 + c4 * 16;
#pragma unroll
    for (int i = 0; i < 4; i++) {
        f32x4 f = *(const f32x4*)(src + i * 4);
#pragma unroll
        for (int j = 0; j < 4; j++) Ls[r][c4 * 16 + i * 4 + j] = f[j];
    }
    __syncthreads();

    short8 va, vb;
#pragma unroll
    for (int j = 0; j < 8; j++) va[j] = f2bf(Ls[c4 * 16 + j][r]);
#pragma unroll
    for (int j = 0; j < 8; j++) vb[j] = f2bf(Ls[c4 * 16 + 8 + j][r]);
    short* dst = out + (size_t)(c0 + r) * DD + r0 + c4 * 16;
    *(short8*)dst = va;
    *(short8*)(dst + 8) = vb;
}

// ---------------------------------------------------------------------------
// Fused QKV projection GEMM, fp32 activations in (conversion fused into
// A-staging: f32x4 loads -> v_cvt_pk_bf16_f32 -> ds_write_b128; B weights
// staged via global_load_lds). 2-phase single-barrier double-buffered LDS
// (T3-min): barrier -> issue next-tile stage into buf^1 -> ds_read/MFMA on
// buf -> A-convert ds_write into buf^1; staging latency hides under MFMA
// (old core barriered immediately after stage issue = latency exposed).
// z==2 (V) swaps MFMA operands -> acc holds C^T -> epilogue stores directly
// to Vbt[bh][dk][t] (same 32B-segment coalescing) -- vtrans kernel deleted.
// Q scaled by 1/sqrt(dk)*log2(e) so attention uses exp2.
// ---------------------------------------------------------------------------
__global__ __launch_bounds__(256, 3)
void gemm_qkv(const float* __restrict__ Aqf, const float* __restrict__ Akf,
              const float* __restrict__ Avf,
              const short* __restrict__ Wqt, const short* __restrict__ Wkt,
              const short* __restrict__ Wvt,
              const float* __restrict__ bq, const float* __restrict__ bk,
              const float* __restrict__ bv,
              short* __restrict__ Qb, short* __restrict__ Kb,
              short* __restrict__ Vbt)
{
    __shared__ short As[2][128 * 32];
    __shared__ short Bs[2][128 * 32];
    const int z = blockIdx.z;
    const float* A  = (z == 0) ? Aqf : (z == 1) ? Akf : Avf;
    const short* Bt = (z == 0) ? Wqt : (z == 1) ? Wkt : Wvt;
    const float* bias = (z == 0) ? bq : (z == 1) ? bk : bv;
    const int m0 = blockIdx.y * 128, n0 = blockIdx.x * 128;

    const int tid = threadIdx.x;
    const int w = tid >> 6, l = tid & 63;
    const int l15 = l & 15, quad = l >> 4;
    const int wm = w >> 1, wn = w & 1;
    const int r = tid >> 2, cseg = tid & 3;

    f32x4 acc[4][4];
#pragma unroll
    for (int i = 0; i < 4; i++)
#pragma unroll
        for (int j = 0; j < 4; j++) acc[i][j] = (f32x4){0.f, 0.f, 0.f, 0.f};

    const float* gA0 = A + (size_t)(m0 + r) * DD + cseg * 8;
    const float* gA1 = gA0 + (size_t)64 * DD;
    const short* gB  = Bt + (size_t)(n0 + r) * DD + cseg * 8;
    const int aoff0 = r * 32 + cseg * 8;
    const int aoff1 = (64 + r) * 32 + cseg * 8;

    // prologue: stage K-tile 0 into buf 0
    glds16(gB + 0,                &Bs[0][w * 512]);
    glds16(gB + (size_t)64 * DD,  &Bs[0][2048 + w * 512]);
    {
        f32x4 a00 = *(const f32x4*)(gA0);
        f32x4 a01 = *(const f32x4*)(gA0 + 4);
        f32x4 a10 = *(const f32x4*)(gA1);
        f32x4 a11 = *(const f32x4*)(gA1 + 4);
        *(short8*)&As[0][aoff0] = cvt8(a00, a01);
        *(short8*)&As[0][aoff1] = cvt8(a10, a11);
    }

    for (int k0 = 0; k0 < DD; k0 += 32) {
        const int cur = (k0 >> 5) & 1;
        __syncthreads();   // buf `cur` staged (vm+lgkm drained); buf^1 readers done
        const bool more = (k0 + 32) < DD;
        f32x4 a00, a01, a10, a11;
        if (more) {
            glds16(gB + k0 + 32,                  &Bs[cur ^ 1][w * 512]);
            glds16(gB + (size_t)64 * DD + k0 + 32, &Bs[cur ^ 1][2048 + w * 512]);
            a00 = *(const f32x4*)(gA0 + k0 + 32);
            a01 = *(const f32x4*)(gA0 + k0 + 36);
            a10 = *(const f32x4*)(gA1 + k0 + 32);
            a11 = *(const f32x4*)(gA1 + k0 + 36);
        }

        short8 bF[4];
#pragma unroll
        for (int ni = 0; ni < 4; ni++)
            bF[ni] = *(const short8*)&Bs[cur][(wn * 64 + ni * 16 + l15) * 32 + quad * 8];
        if (z != 2) {
#pragma unroll
            for (int mi = 0; mi < 4; mi++) {
                short8 aF = *(const short8*)&As[cur][(wm * 64 + mi * 16 + l15) * 32 + quad * 8];
#pragma unroll
                for (int ni = 0; ni < 4; ni++)
                    acc[mi][ni] = __builtin_amdgcn_mfma_f32_16x16x32_bf16(aF, bF[ni], acc[mi][ni], 0, 0, 0);
            }
        } else {
            // swapped operands: acc[ni][mi] = C^T fragment (rows = n, cols = m)
#pragma unroll
            for (int mi = 0; mi < 4; mi++) {
                short8 aF = *(const short8*)&As[cur][(wm * 64 + mi * 16 + l15) * 32 + quad * 8];
#pragma unroll
                for (int ni = 0; ni < 4; ni++)
                    acc[ni][mi] = __builtin_amdgcn_mfma_f32_16x16x32_bf16(bF[ni], aF, acc[ni][mi], 0, 0, 0);
            }
        }

        if (more) {
            *(short8*)&As[cur ^ 1][aoff0] = cvt8(a00, a01);
            *(short8*)&As[cur ^ 1][aoff1] = cvt8(a10, a11);
        }
    }

    if (z != 2) {
        short* dst = (z == 0) ? Qb : Kb;
        const float scale = (z == 0) ? 0.1803368801f : 1.0f;
#pragma unroll
        for (int mi = 0; mi < 4; mi++) {
#pragma unroll
            for (int reg = 0; reg < 4; reg++) {
                int m = m0 + wm * 64 + mi * 16 + quad * 4 + reg;
                int b = m >> 11, t = m & 2047;
#pragma unroll
                for (int ni = 0; ni < 4; ni++) {
                    int n = n0 + wn * 64 + ni * 16 + l15;
                    float vv = (acc[mi][ni][reg] + bias[n]) * scale;
                    int h = n >> 6, dk = n & 63;
                    dst[((size_t)(b * HH + h) * TT + t) * DKK + dk] = f2bf(vv);
                }
            }
        }
    } else {
        // acc[ni][mi]: row (quad*4+reg) = n-side, col l15 = m-side
        const int b = m0 >> 11;
        const int tl0 = (m0 & 2047) + wm * 64;
#pragma unroll
        for (int ni = 0; ni < 4; ni++) {
#pragma unroll
            for (int reg = 0; reg < 4; reg++) {
                int n = n0 + wn * 64 + ni * 16 + quad * 4 + reg;
                int h = n >> 6, dk = n & 63;
                float bb = bias[n];
                short* vrow = Vbt + ((size_t)(b * HH + h) * DKK + dk) * SSQ;
#pragma unroll
                for (int mi = 0; mi < 4; mi++) {
                    int t = tl0 + mi * 16 + l15;
                    vrow[t] = f2bf(acc[ni][mi][reg] + bb);
                }
            }
        }
    }
}

// ---------------------------------------------------------------------------
// Output projection GEMM: out[M][D] = Ab @ Wot^T + bo, fp32 out.
// 64x128 tiles, grid (8,64) = 512 blocks = 2 blocks/CU. 2-phase
// single-barrier double-buffered LDS (same recipe as gemm_qkv).
// ---------------------------------------------------------------------------
__global__ __launch_bounds__(256, 3)
void gemm_out(const short* __restrict__ Ab, const short* __restrict__ Wot,
              const float* __restrict__ bo, float* __restrict__ out)
{
    __shared__ short As[2][64 * 32];
    __shared__ short Bs[2][128 * 32];
    const int m0 = blockIdx.y * 64, n0 = blockIdx.x * 128;
    const int tid = threadIdx.x;
    const int w = tid >> 6, l = tid & 63;
    const int l15 = l & 15, quad = l >> 4;
    const int wm = w >> 1, wn = w & 1;

    f32x4 acc[2][4];
#pragma unroll
    for (int i = 0; i < 2; i++)
#pragma unroll
        for (int j = 0; j < 4; j++) acc[i][j] = (f32x4){0.f, 0.f, 0.f, 0.f};

    const int r = tid >> 2, cseg = tid & 3;
    const short* gA = Ab + (size_t)(m0 + r) * DD + cseg * 8;
    const short* gB = Wot + (size_t)(n0 + r) * DD + cseg * 8;

    // prologue: stage K-tile 0 into buf 0
    glds16(gA + 0,               &As[0][w * 512]);
    glds16(gB + 0,               &Bs[0][w * 512]);
    glds16(gB + (size_t)64 * DD, &Bs[0][2048 + w * 512]);

    for (int k0 = 0; k0 < DD; k0 += 32) {
        const int cur = (k0 >> 5) & 1;
        __syncthreads();
        if (k0 + 32 < DD) {
            glds16(gA + k0 + 32,                   &As[cur ^ 1][w * 512]);
            glds16(gB + k0 + 32,                   &Bs[cur ^ 1][w * 512]);
            glds16(gB + (size_t)64 * DD + k0 + 32, &Bs[cur ^ 1][2048 + w * 512]);
        }

        short8 bF[4];
#pragma unroll
        for (int ni = 0; ni < 4; ni++)
            bF[ni] = *(const short8*)&Bs[cur][(wn * 64 + ni * 16 + l15) * 32 + quad * 8];
#pragma unroll
        for (int mi = 0; mi < 2; mi++) {
            short8 aF = *(const short8*)&As[cur][(wm * 32 + mi * 16 + l15) * 32 + quad * 8];
#pragma unroll
            for (int ni = 0; ni < 4; ni++)
                acc[mi][ni] = __builtin_amdgcn_mfma_f32_16x16x32_bf16(aF, bF[ni], acc[mi][ni], 0, 0, 0);
        }
    }

#pragma unroll
    for (int mi = 0; mi < 2; mi++) {
#pragma unroll
        for (int reg = 0; reg < 4; reg++) {
            int m = m0 + wm * 32 + mi * 16 + quad * 4 + reg;
#pragma unroll
            for (int ni = 0; ni < 4; ni++) {
                int n = n0 + wn * 64 + ni * 16 + l15;
                out[(size_t)m * DD + n] = acc[mi][ni][reg] + bo[n];
            }
        }
    }
}

// ---------------------------------------------------------------------------
// bf16 MFMA flash attention, split-S ACROSS BLOCKS: grid (16, 32, 2), z=half
// owns s in [1024*half, 1024*half+1024). Unchanged from round 5 (proven).
// ---------------------------------------------------------------------------
__global__ __launch_bounds__(256, 4)
void attn_mfma(const short* __restrict__ Qb, const short* __restrict__ Kb,
               const short* __restrict__ Vbt,
               float* __restrict__ O1, float* __restrict__ O2,
               float* __restrict__ l1, float* __restrict__ l2)
{
    // [dbuf][{K|V}] each 64x72 shorts: K at dbo, V at dbo+4608
    __shared__ short KV[2 * 2 * 64 * 72];   // 36864 B

    const int tid = threadIdx.x;
    const int w = tid >> 6, l = tid & 63;
    const int l15 = l & 15, quad = l >> 4;

    // bijective XCD swizzle: fid -> (tile, bh); XCD k gets bh in [4k,4k+4)
    const int fid = blockIdx.y * 16 + blockIdx.x;
    const int swz = (fid & 7) * 64 + (fid >> 3);
    const int t0 = (swz & 15) * 128;
    const int bh = swz >> 4;
    const int half = blockIdx.z;
    const size_t hb = (size_t)bh * SSQ * DKK;
    const int r = tid >> 2, c4 = tid & 3;
    const int sbase = half * 1024;

    // ---- Q fragments direct from global (B-operand layout, reused 16 tiles)
    short8 qf[2][2];
#pragma unroll
    for (int mf = 0; mf < 2; mf++)
#pragma unroll
        for (int kk = 0; kk < 2; kk++)
            qf[mf][kk] = *(const short8*)(Qb + hb +
                (size_t)(t0 + 32 * w + 16 * mf + l15) * DKK + kk * 32 + quad * 8);

    // ---- prefetch K/V tile 0 of this half's s-range ----
    const short* gkb = Kb + hb + (size_t)(sbase + r) * DKK + c4 * 16;
    const short* gvb = Vbt + hb + (size_t)r * SSQ + sbase + c4 * 16;
    short8 kr0 = *(const short8*)(gkb + 0);
    short8 kr1 = *(const short8*)(gkb + 8);
    short8 vr0 = *(const short8*)(gvb + 0);
    short8 vr1 = *(const short8*)(gvb + 8);

    f32x4 o[2][4];
#pragma unroll
    for (int mf = 0; mf < 2; mf++)
#pragma unroll
        for (int j = 0; j < 4; j++) o[mf][j] = (f32x4){0.f, 0.f, 0.f, 0.f};
    f32x4 lacc[2] = {(f32x4){0.f, 0.f, 0.f, 0.f}, (f32x4){0.f, 0.f, 0.f, 0.f}};
    const short8 ones = {(short)0x3F80, (short)0x3F80, (short)0x3F80, (short)0x3F80,
                         (short)0x3F80, (short)0x3F80, (short)0x3F80, (short)0x3F80};

    short* skb = KV + r * 72 + c4 * 16;   // staging write base

    for (int s0 = 0; s0 < 1024; s0 += 64) {
        const int dbo = (s0 & 64) ? 9216 : 0;
        // write current K/V regs into buffer `dbo`
        *(short8*)(skb + dbo)          = kr0;
        *(short8*)(skb + dbo + 8)      = kr1;
        *(short8*)(skb + dbo + 4608)   = vr0;
        *(short8*)(skb + dbo + 4616)   = vr1;
        // issue next-tile global loads (covered by this tile's compute)
        if (s0 + 64 < 1024) {
            const short* gk = gkb + (size_t)(s0 + 64) * DKK;
            const short* gv = gvb + (s0 + 64);
            kr0 = *(const short8*)(gk + 0);
            kr1 = *(const short8*)(gk + 8);
            vr0 = *(const short8*)(gv + 0);
            vr1 = *(const short8*)(gv + 8);
        }
        __syncthreads();          // tile `dbo` visible; prev-buffer readers done
        const short* kb_ = KV + dbo;
        const short* vb_ = kb_ + 4608;

        // ---- S^T = K Q^T : lane holds q-row l15, s = 16np+4quad+reg ----
        f32x4 sc[4][2];
#pragma unroll
        for (int np = 0; np < 4; np++)
#pragma unroll
            for (int mf = 0; mf < 2; mf++) sc[np][mf] = (f32x4){0.f, 0.f, 0.f, 0.f};
        __builtin_amdgcn_s_setprio(1);
#pragma unroll
        for (int kk = 0; kk < 2; kk++) {
#pragma unroll
            for (int np = 0; np < 4; np++) {
                short8 aK = *(const short8*)&kb_[(16 * np + l15) * 72 + kk * 32 + quad * 8];
                sc[np][0] = __builtin_amdgcn_mfma_f32_16x16x32_bf16(aK, qf[0][kk], sc[np][0], 0, 0, 0);
                sc[np][1] = __builtin_amdgcn_mfma_f32_16x16x32_bf16(aK, qf[1][kk], sc[np][1], 0, 0, 0);
            }
        }
        __builtin_amdgcn_s_setprio(0);

        // ---- P = exp2(S); inline pack + permlane into PV A-frags ----
        short8 pa[2][2];
#pragma unroll
        for (int mf = 0; mf < 2; mf++) {
#pragma unroll
            for (int kk = 0; kk < 2; kk++) {
                u32x4 wd;
#pragma unroll
                for (int b = 0; b < 2; b++) {
                    float p00 = __builtin_amdgcn_exp2f(sc[2 * kk][mf][2 * b]);
                    float p01 = __builtin_amdgcn_exp2f(sc[2 * kk][mf][2 * b + 1]);
                    float p10 = __builtin_amdgcn_exp2f(sc[2 * kk + 1][mf][2 * b]);
                    float p11 = __builtin_amdgcn_exp2f(sc[2 * kk + 1][mf][2 * b + 1]);
                    unsigned Xw = pk2(p00, p01);
                    unsigned Yw = pk2(p10, p11);
                    uint2v s1 = __builtin_amdgcn_permlane32_swap(Xw, Yw, false, false);
                    uint2v s2 = __builtin_amdgcn_permlane16_swap(s1[0], s1[1], false, false);
                    wd[b]     = s2[0];
                    wd[2 + b] = s2[1];
                }
                pa[mf][kk] = __builtin_bit_cast(short8, wd);
            }
        }

        // ---- O += P V ; lacc += P * ones (row-sum l on matrix pipe) ----
        __builtin_amdgcn_s_setprio(1);
#pragma unroll
        for (int kk = 0; kk < 2; kk++) {
            lacc[0] = __builtin_amdgcn_mfma_f32_16x16x32_bf16(pa[0][kk], ones, lacc[0], 0, 0, 0);
            lacc[1] = __builtin_amdgcn_mfma_f32_16x16x32_bf16(pa[1][kk], ones, lacc[1], 0, 0, 0);
#pragma unroll
            for (int np = 0; np < 4; np++) {
                short8 bV = *(const short8*)&vb_[(16 * np + l15) * 72 + kk * 32 + quad * 8];
                o[0][np] = __builtin_amdgcn_mfma_f32_16x16x32_bf16(pa[0][kk], bV, o[0][np], 0, 0, 0);
                o[1][np] = __builtin_amdgcn_mfma_f32_16x16x32_bf16(pa[1][kk], bV, o[1][np], 0, 0, 0);
            }
        }
        __builtin_amdgcn_s_setprio(0);
    }

    // ---- epilogue: write unnormalized partials + row-sums ----
    float* O = half ? O2 : O1;
    float* L = half ? l2 : l1;
    const size_t rowb = (size_t)bh * TT;
#pragma unroll
    for (int mf = 0; mf < 2; mf++) {
#pragma unroll
        for (int reg = 0; reg < 4; reg++) {
            int t = t0 + 32 * w + 16 * mf + quad * 4 + reg;
            if (l15 == 0) L[rowb + t] = lacc[mf][reg];
            float* orow = O + (rowb + t) * DKK;
#pragma unroll
            for (int np = 0; np < 4; np++)
                orow[16 * np + l15] = o[mf][np][reg];
        }
    }
}

// ---------------------------------------------------------------------------
// Split-S combine: Ab[b][t][h][dk] = f2bf((O1+O2) / (l1+l2)).
// grid 2048 x 256 thr; thread handles 8 consecutive dk.
// ---------------------------------------------------------------------------
__global__ __launch_bounds__(256)
void combine_norm(const float* __restrict__ O1, const float* __restrict__ O2,
                  const float* __restrict__ l1, const float* __restrict__ l2,
                  short* __restrict__ Ab)
{
    size_t g = (size_t)blockIdx.x * 256 + threadIdx.x;
    size_t i0 = g * 8;
    int bh = (int)(i0 >> 17);          // / (2048*64)
    int t  = (int)((i0 >> 6) & 2047);
    int dk = (int)(i0 & 63);
    float inv = 1.f / (l1[(size_t)bh * TT + t] + l2[(size_t)bh * TT + t]);
    f32x4 a0 = *(const f32x4*)(O1 + i0);
    f32x4 a1 = *(const f32x4*)(O1 + i0 + 4);
    f32x4 b0 = *(const f32x4*)(O2 + i0);
    f32x4 b1 = *(const f32x4*)(O2 + i0 + 4);
    short8 v;
#pragma unroll
    for (int j = 0; j < 4; j++) v[j] = f2bf((a0[j] + b0[j]) * inv);
#pragma unroll
    for (int j = 0; j < 4; j++) v[4 + j] = f2bf((a1[j] + b1[j]) * inv);
    int b = bh >> 4, h = bh & 15;
    *(short8*)(Ab + (((size_t)(b * TT + t) * HH + h) * DKK + dk)) = v;
}

// ---------------------------------------------------------------------------
extern "C" void kernel_launch(void* const* d_in, const int* in_sizes, int n_in,
                              void* d_out, int out_size, void* d_ws, size_t ws_size,
                              hipStream_t stream)
{
    const float* query = (const float*)d_in[0];
    const float* value = (const float*)d_in[1];
    const float* key   = (const float*)d_in[2];
    const float* Wq    = (const float*)d_in[3];
    const float* bq    = (const float*)d_in[4];
    const float* Wk    = (const float*)d_in[5];
    const float* bk    = (const float*)d_in[6];
    const float* Wv    = (const float*)d_in[7];
    const float* bv    = (const float*)d_in[8];
    const float* Wo    = (const float*)d_in[9];
    const float* bo    = (const float*)d_in[10];
    float* out = (float*)d_out;

    const size_t actE = (size_t)MM * DD;    // 4.19M elems
    const size_t wE   = (size_t)DD * NN;    // 1.05M elems
    short* p = (short*)d_ws;
    short* Wqt  = p; p += wE;
    short* Wkt  = p; p += wE;
    short* Wvt  = p; p += wE;
    short* Wot  = p; p += wE;
    short* Qb   = p; p += actE;
    short* Kb   = p; p += actE;
    short* Vbt  = p; p += actE;
    short* Ab   = p; p += actE;
    float* O1f  = (float*)p; p += 2 * actE;
    float* O2f  = (float*)p; p += 2 * actE;
    float* l1f  = (float*)p; p += 4 * (size_t)BB * HH * TT;  // 2 float arrays
    float* l2f  = l1f + (size_t)BB * HH * TT;

    dim3 blk(256);

    // 1. weights fp32 [K][N] -> bf16 [N][K]
    wtrans<<<dim3(16, 16, 4), blk, 0, stream>>>(Wq, Wk, Wv, Wo, Wqt, Wkt, Wvt, Wot);

    // 2. fused QKV projections from fp32 activations; V written transposed
    gemm_qkv<<<dim3(NN / 128, MM / 128, 3), blk, 0, stream>>>(
        query, key, value, Wqt, Wkt, Wvt, bq, bk, bv, Qb, Kb, Vbt);

    // 3. flash attention, split-S across z=2 -> f32 partials
    attn_mfma<<<dim3(TT / 128, BB * HH, 2), blk, 0, stream>>>(
        Qb, Kb, Vbt, O1f, O2f, l1f, l2f);

    // 4. combine + normalize -> bf16 Ab
    combine_norm<<<dim3((unsigned)(actE / 2048)), blk, 0, stream>>>(
        O1f, O2f, l1f, l2f, Ab);

    // 5. output projection -> fp32 out
    gemm_out<<<dim3(NN / 128, MM / 64), blk, 0, stream>>>(Ab, Wot, bo, out);
}

// Round 7
// 249.066 us; speedup vs baseline: 1.0176x; 1.0176x over previous
//
#include <hip/hip_runtime.h>
#include <math.h>

#define BB  2
#define TT  2048
#define SSQ 2048
#define DD  1024
#define HH  16
#define DKK 64
#define MM  (BB*TT)      // 4096 rows of activations
#define NN  (HH*DKK)     // 1024 proj width

typedef __attribute__((ext_vector_type(8))) short short8;
typedef __attribute__((ext_vector_type(4))) float f32x4;
typedef __attribute__((ext_vector_type(2))) unsigned int uint2v;
typedef __attribute__((ext_vector_type(4))) unsigned int u32x4;

__device__ __forceinline__ short f2bf(float x) {
    unsigned u = __builtin_bit_cast(unsigned, x);
    unsigned r = (u + 0x7FFFu + ((u >> 16) & 1u)) >> 16;
    return (short)r;
}

// pack two f32 into a bf16x2 word by truncation
__device__ __forceinline__ unsigned pk2(float lo, float hi) {
    return (__builtin_bit_cast(unsigned, hi) & 0xFFFF0000u) |
           (__builtin_bit_cast(unsigned, lo) >> 16);
}

// 8x f32 -> 8x bf16 via v_cvt_pk_bf16_f32 (RNE), 4 instrs
__device__ __forceinline__ short8 cvt8(f32x4 x, f32x4 y) {
    unsigned r0, r1, r2, r3;
    asm("v_cvt_pk_bf16_f32 %0, %1, %2" : "=v"(r0) : "v"(x[0]), "v"(x[1]));
    asm("v_cvt_pk_bf16_f32 %0, %1, %2" : "=v"(r1) : "v"(x[2]), "v"(x[3]));
    asm("v_cvt_pk_bf16_f32 %0, %1, %2" : "=v"(r2) : "v"(y[0]), "v"(y[1]));
    asm("v_cvt_pk_bf16_f32 %0, %1, %2" : "=v"(r3) : "v"(y[2]), "v"(y[3]));
    u32x4 r;
    r[0] = r0; r[1] = r1; r[2] = r2; r[3] = r3;
    return __builtin_bit_cast(short8, r);
}

__device__ __forceinline__ void glds16(const void* g, void* l) {
    __builtin_amdgcn_global_load_lds(
        (const __attribute__((address_space(1))) void*)g,
        (__attribute__((address_space(3))) void*)l, 16, 0, 0);
}

// ---------------------------------------------------------------------------
// Weight transpose+convert: fp32 [K=1024][N=1024] -> bf16 [N][K].
// grid (16,16,4): z picks which weight.
// ---------------------------------------------------------------------------
__global__ __launch_bounds__(256)
void wtrans(const float* __restrict__ w0, const float* __restrict__ w1,
            const float* __restrict__ w2, const float* __restrict__ w3,
            short* __restrict__ t0, short* __restrict__ t1,
            short* __restrict__ t2, short* __restrict__ t3)
{
    __shared__ float Ls[64][65];
    int z = blockIdx.z;
    const float* in = (z == 0) ? w0 : (z == 1) ? w1 : (z == 2) ? w2 : w3;
    short* out = (z == 0) ? t0 : (z == 1) ? t1 : (z == 2) ? t2 : t3;
    const int r0 = blockIdx.y * 64, c0 = blockIdx.x * 64;
    const int t = threadIdx.x;
    const int r = t >> 2, c4 = t & 3;

    const float* src = in + (size_t)(r0 + r) * DD + c0 + c4 * 16;
#pragma unroll
    for (int i = 0; i < 4; i++) {
        f32x4 f = *(const f32x4*)(src + i * 4);
#pragma unroll
        for (int j = 0; j < 4; j++) Ls[r][c4 * 16 + i * 4 + j] = f[j];
    }
    __syncthreads();

    short8 va, vb;
#pragma unroll
    for (int j = 0; j < 8; j++) va[j] = f2bf(Ls[c4 * 16 + j][r]);
#pragma unroll
    for (int j = 0; j < 8; j++) vb[j] = f2bf(Ls[c4 * 16 + 8 + j][r]);
    short* dst = out + (size_t)(c0 + r) * DD + r0 + c4 * 16;
    *(short8*)dst = va;
    *(short8*)(dst + 8) = vb;
}

// ---------------------------------------------------------------------------
// Fused QKV projection GEMM, fp32 activations in (conversion fused into
// A-staging), 2-phase single-barrier double-buffered LDS. V (z==2) uses
// swapped MFMA operands -> stores directly to Vbt[bh][dk][t].
// XCD SWIZZLE (round-6 fix): dispatch linear id d -> XCD d%8; decode so XCD
// k owns m-blocks [4k,4k+4) for ALL z and n, m-fastest. A panel per XCD per
// z = 2MB (L2-fit, HBM-fetched once, 8x n-reuse from L2); B tile reused 4x
// by consecutive m-blocks. Fixes round-6's 202MB FETCH (8-way cross-XCD A
// amplification: n-blocks sharing an A panel round-robined onto 8 L2s).
// Q scaled by 1/sqrt(dk)*log2(e) so attention uses exp2.
// ---------------------------------------------------------------------------
__global__ __launch_bounds__(256, 3)
void gemm_qkv(const float* __restrict__ Aqf, const float* __restrict__ Akf,
              const float* __restrict__ Avf,
              const short* __restrict__ Wqt, const short* __restrict__ Wkt,
              const short* __restrict__ Wvt,
              const float* __restrict__ bq, const float* __restrict__ bk,
              const float* __restrict__ bv,
              short* __restrict__ Qb, short* __restrict__ Kb,
              short* __restrict__ Vbt)
{
    __shared__ short As[2][128 * 32];
    __shared__ short Bs[2][128 * 32];

    // bijective XCD swizzle over 768 blocks: d%8 = XCD k; j = d/8 in [0,96):
    // m_local = j&3 (fastest), n_blk = (j>>2)&7, z = j>>5; m_blk = 4k+m_local
    const int d = blockIdx.x + 8 * blockIdx.y + 256 * blockIdx.z;
    const int kx = d & 7, j = d >> 3;
    const int z = j >> 5;
    const int n0 = ((j >> 2) & 7) * 128;
    const int m0 = (4 * kx + (j & 3)) * 128;

    const float* A  = (z == 0) ? Aqf : (z == 1) ? Akf : Avf;
    const short* Bt = (z == 0) ? Wqt : (z == 1) ? Wkt : Wvt;
    const float* bias = (z == 0) ? bq : (z == 1) ? bk : bv;

    const int tid = threadIdx.x;
    const int w = tid >> 6, l = tid & 63;
    const int l15 = l & 15, quad = l >> 4;
    const int wm = w >> 1, wn = w & 1;
    const int r = tid >> 2, cseg = tid & 3;

    f32x4 acc[4][4];
#pragma unroll
    for (int i = 0; i < 4; i++)
#pragma unroll
        for (int jj = 0; jj < 4; jj++) acc[i][jj] = (f32x4){0.f, 0.f, 0.f, 0.f};

    const float* gA0 = A + (size_t)(m0 + r) * DD + cseg * 8;
    const float* gA1 = gA0 + (size_t)64 * DD;
    const short* gB  = Bt + (size_t)(n0 + r) * DD + cseg * 8;
    const int aoff0 = r * 32 + cseg * 8;
    const int aoff1 = (64 + r) * 32 + cseg * 8;

    // prologue: stage K-tile 0 into buf 0
    glds16(gB + 0,                &Bs[0][w * 512]);
    glds16(gB + (size_t)64 * DD,  &Bs[0][2048 + w * 512]);
    {
        f32x4 a00 = *(const f32x4*)(gA0);
        f32x4 a01 = *(const f32x4*)(gA0 + 4);
        f32x4 a10 = *(const f32x4*)(gA1);
        f32x4 a11 = *(const f32x4*)(gA1 + 4);
        *(short8*)&As[0][aoff0] = cvt8(a00, a01);
        *(short8*)&As[0][aoff1] = cvt8(a10, a11);
    }

    for (int k0 = 0; k0 < DD; k0 += 32) {
        const int cur = (k0 >> 5) & 1;
        __syncthreads();   // buf `cur` staged (vm+lgkm drained); buf^1 readers done
        const bool more = (k0 + 32) < DD;
        f32x4 a00, a01, a10, a11;
        if (more) {
            glds16(gB + k0 + 32,                  &Bs[cur ^ 1][w * 512]);
            glds16(gB + (size_t)64 * DD + k0 + 32, &Bs[cur ^ 1][2048 + w * 512]);
            a00 = *(const f32x4*)(gA0 + k0 + 32);
            a01 = *(const f32x4*)(gA0 + k0 + 36);
            a10 = *(const f32x4*)(gA1 + k0 + 32);
            a11 = *(const f32x4*)(gA1 + k0 + 36);
        }

        short8 bF[4];
#pragma unroll
        for (int ni = 0; ni < 4; ni++)
            bF[ni] = *(const short8*)&Bs[cur][(wn * 64 + ni * 16 + l15) * 32 + quad * 8];
        if (z != 2) {
#pragma unroll
            for (int mi = 0; mi < 4; mi++) {
                short8 aF = *(const short8*)&As[cur][(wm * 64 + mi * 16 + l15) * 32 + quad * 8];
#pragma unroll
                for (int ni = 0; ni < 4; ni++)
                    acc[mi][ni] = __builtin_amdgcn_mfma_f32_16x16x32_bf16(aF, bF[ni], acc[mi][ni], 0, 0, 0);
            }
        } else {
            // swapped operands: acc[ni][mi] = C^T fragment (rows = n, cols = m)
#pragma unroll
            for (int mi = 0; mi < 4; mi++) {
                short8 aF = *(const short8*)&As[cur][(wm * 64 + mi * 16 + l15) * 32 + quad * 8];
#pragma unroll
                for (int ni = 0; ni < 4; ni++)
                    acc[ni][mi] = __builtin_amdgcn_mfma_f32_16x16x32_bf16(bF[ni], aF, acc[ni][mi], 0, 0, 0);
            }
        }

        if (more) {
            *(short8*)&As[cur ^ 1][aoff0] = cvt8(a00, a01);
            *(short8*)&As[cur ^ 1][aoff1] = cvt8(a10, a11);
        }
    }

    if (z != 2) {
        short* dst = (z == 0) ? Qb : Kb;
        const float scale = (z == 0) ? 0.1803368801f : 1.0f;
#pragma unroll
        for (int mi = 0; mi < 4; mi++) {
#pragma unroll
            for (int reg = 0; reg < 4; reg++) {
                int m = m0 + wm * 64 + mi * 16 + quad * 4 + reg;
                int b = m >> 11, t = m & 2047;
#pragma unroll
                for (int ni = 0; ni < 4; ni++) {
                    int n = n0 + wn * 64 + ni * 16 + l15;
                    float vv = (acc[mi][ni][reg] + bias[n]) * scale;
                    int h = n >> 6, dk = n & 63;
                    dst[((size_t)(b * HH + h) * TT + t) * DKK + dk] = f2bf(vv);
                }
            }
        }
    } else {
        // acc[ni][mi]: row (quad*4+reg) = n-side, col l15 = m-side
        const int b = m0 >> 11;
        const int tl0 = (m0 & 2047) + wm * 64;
#pragma unroll
        for (int ni = 0; ni < 4; ni++) {
#pragma unroll
            for (int reg = 0; reg < 4; reg++) {
                int n = n0 + wn * 64 + ni * 16 + quad * 4 + reg;
                int h = n >> 6, dk = n & 63;
                float bb = bias[n];
                short* vrow = Vbt + ((size_t)(b * HH + h) * DKK + dk) * SSQ;
#pragma unroll
                for (int mi = 0; mi < 4; mi++) {
                    int t = tl0 + mi * 16 + l15;
                    vrow[t] = f2bf(acc[ni][mi][reg] + bb);
                }
            }
        }
    }
}

// ---------------------------------------------------------------------------
// Output projection GEMM: out[M][D] = Ab @ Wot^T + bo, fp32 out.
// 64x128 tiles, 512 blocks. XCD swizzle: XCD k owns m-blocks [8k,8k+8)
// (m-fastest) -> Ab chunk 1MB + Wot 2MB per XCD, both L2-fit.
// 2-phase single-barrier double-buffered LDS.
// ---------------------------------------------------------------------------
__global__ __launch_bounds__(256, 3)
void gemm_out(const short* __restrict__ Ab, const short* __restrict__ Wot,
              const float* __restrict__ bo, float* __restrict__ out)
{
    __shared__ short As[2][64 * 32];
    __shared__ short Bs[2][128 * 32];

    // bijective XCD swizzle over 512 blocks: d%8 = XCD k; j = d/8 in [0,64):
    // m_local = j&7 (fastest), n_blk = j>>3; m_blk = 8k + m_local
    const int d = blockIdx.x + 8 * blockIdx.y;
    const int kx = d & 7, j = d >> 3;
    const int m0 = (8 * kx + (j & 7)) * 64;
    const int n0 = (j >> 3) * 128;

    const int tid = threadIdx.x;
    const int w = tid >> 6, l = tid & 63;
    const int l15 = l & 15, quad = l >> 4;
    const int wm = w >> 1, wn = w & 1;

    f32x4 acc[2][4];
#pragma unroll
    for (int i = 0; i < 2; i++)
#pragma unroll
        for (int jj = 0; jj < 4; jj++) acc[i][jj] = (f32x4){0.f, 0.f, 0.f, 0.f};

    const int r = tid >> 2, cseg = tid & 3;
    const short* gA = Ab + (size_t)(m0 + r) * DD + cseg * 8;
    const short* gB = Wot + (size_t)(n0 + r) * DD + cseg * 8;

    // prologue: stage K-tile 0 into buf 0
    glds16(gA + 0,               &As[0][w * 512]);
    glds16(gB + 0,               &Bs[0][w * 512]);
    glds16(gB + (size_t)64 * DD, &Bs[0][2048 + w * 512]);

    for (int k0 = 0; k0 < DD; k0 += 32) {
        const int cur = (k0 >> 5) & 1;
        __syncthreads();
        if (k0 + 32 < DD) {
            glds16(gA + k0 + 32,                   &As[cur ^ 1][w * 512]);
            glds16(gB + k0 + 32,                   &Bs[cur ^ 1][w * 512]);
            glds16(gB + (size_t)64 * DD + k0 + 32, &Bs[cur ^ 1][2048 + w * 512]);
        }

        short8 bF[4];
#pragma unroll
        for (int ni = 0; ni < 4; ni++)
            bF[ni] = *(const short8*)&Bs[cur][(wn * 64 + ni * 16 + l15) * 32 + quad * 8];
#pragma unroll
        for (int mi = 0; mi < 2; mi++) {
            short8 aF = *(const short8*)&As[cur][(wm * 32 + mi * 16 + l15) * 32 + quad * 8];
#pragma unroll
            for (int ni = 0; ni < 4; ni++)
                acc[mi][ni] = __builtin_amdgcn_mfma_f32_16x16x32_bf16(aF, bF[ni], acc[mi][ni], 0, 0, 0);
        }
    }

#pragma unroll
    for (int mi = 0; mi < 2; mi++) {
#pragma unroll
        for (int reg = 0; reg < 4; reg++) {
            int m = m0 + wm * 32 + mi * 16 + quad * 4 + reg;
#pragma unroll
            for (int ni = 0; ni < 4; ni++) {
                int n = n0 + wn * 64 + ni * 16 + l15;
                out[(size_t)m * DD + n] = acc[mi][ni][reg] + bo[n];
            }
        }
    }
}

// ---------------------------------------------------------------------------
// bf16 MFMA flash attention, split-S ACROSS BLOCKS: grid (16, 32, 2), z=half
// owns s in [1024*half, 1024*half+1024). Unchanged from round 5 (proven).
// ---------------------------------------------------------------------------
__global__ __launch_bounds__(256, 4)
void attn_mfma(const short* __restrict__ Qb, const short* __restrict__ Kb,
               const short* __restrict__ Vbt,
               float* __restrict__ O1, float* __restrict__ O2,
               float* __restrict__ l1, float* __restrict__ l2)
{
    // [dbuf][{K|V}] each 64x72 shorts: K at dbo, V at dbo+4608
    __shared__ short KV[2 * 2 * 64 * 72];   // 36864 B

    const int tid = threadIdx.x;
    const int w = tid >> 6, l = tid & 63;
    const int l15 = l & 15, quad = l >> 4;

    // bijective XCD swizzle: fid -> (tile, bh); XCD k gets bh in [4k,4k+4)
    const int fid = blockIdx.y * 16 + blockIdx.x;
    const int swz = (fid & 7) * 64 + (fid >> 3);
    const int t0 = (swz & 15) * 128;
    const int bh = swz >> 4;
    const int half = blockIdx.z;
    const size_t hb = (size_t)bh * SSQ * DKK;
    const int r = tid >> 2, c4 = tid & 3;
    const int sbase = half * 1024;

    // ---- Q fragments direct from global (B-operand layout, reused 16 tiles)
    short8 qf[2][2];
#pragma unroll
    for (int mf = 0; mf < 2; mf++)
#pragma unroll
        for (int kk = 0; kk < 2; kk++)
            qf[mf][kk] = *(const short8*)(Qb + hb +
                (size_t)(t0 + 32 * w + 16 * mf + l15) * DKK + kk * 32 + quad * 8);

    // ---- prefetch K/V tile 0 of this half's s-range ----
    const short* gkb = Kb + hb + (size_t)(sbase + r) * DKK + c4 * 16;
    const short* gvb = Vbt + hb + (size_t)r * SSQ + sbase + c4 * 16;
    short8 kr0 = *(const short8*)(gkb + 0);
    short8 kr1 = *(const short8*)(gkb + 8);
    short8 vr0 = *(const short8*)(gvb + 0);
    short8 vr1 = *(const short8*)(gvb + 8);

    f32x4 o[2][4];
#pragma unroll
    for (int mf = 0; mf < 2; mf++)
#pragma unroll
        for (int j = 0; j < 4; j++) o[mf][j] = (f32x4){0.f, 0.f, 0.f, 0.f};
    f32x4 lacc[2] = {(f32x4){0.f, 0.f, 0.f, 0.f}, (f32x4){0.f, 0.f, 0.f, 0.f}};
    const short8 ones = {(short)0x3F80, (short)0x3F80, (short)0x3F80, (short)0x3F80,
                         (short)0x3F80, (short)0x3F80, (short)0x3F80, (short)0x3F80};

    short* skb = KV + r * 72 + c4 * 16;   // staging write base

    for (int s0 = 0; s0 < 1024; s0 += 64) {
        const int dbo = (s0 & 64) ? 9216 : 0;
        // write current K/V regs into buffer `dbo`
        *(short8*)(skb + dbo)          = kr0;
        *(short8*)(skb + dbo + 8)      = kr1;
        *(short8*)(skb + dbo + 4608)   = vr0;
        *(short8*)(skb + dbo + 4616)   = vr1;
        // issue next-tile global loads (covered by this tile's compute)
        if (s0 + 64 < 1024) {
            const short* gk = gkb + (size_t)(s0 + 64) * DKK;
            const short* gv = gvb + (s0 + 64);
            kr0 = *(const short8*)(gk + 0);
            kr1 = *(const short8*)(gk + 8);
            vr0 = *(const short8*)(gv + 0);
            vr1 = *(const short8*)(gv + 8);
        }
        __syncthreads();          // tile `dbo` visible; prev-buffer readers done
        const short* kb_ = KV + dbo;
        const short* vb_ = kb_ + 4608;

        // ---- S^T = K Q^T : lane holds q-row l15, s = 16np+4quad+reg ----
        f32x4 sc[4][2];
#pragma unroll
        for (int np = 0; np < 4; np++)
#pragma unroll
            for (int mf = 0; mf < 2; mf++) sc[np][mf] = (f32x4){0.f, 0.f, 0.f, 0.f};
        __builtin_amdgcn_s_setprio(1);
#pragma unroll
        for (int kk = 0; kk < 2; kk++) {
#pragma unroll
            for (int np = 0; np < 4; np++) {
                short8 aK = *(const short8*)&kb_[(16 * np + l15) * 72 + kk * 32 + quad * 8];
                sc[np][0] = __builtin_amdgcn_mfma_f32_16x16x32_bf16(aK, qf[0][kk], sc[np][0], 0, 0, 0);
                sc[np][1] = __builtin_amdgcn_mfma_f32_16x16x32_bf16(aK, qf[1][kk], sc[np][1], 0, 0, 0);
            }
        }
        __builtin_amdgcn_s_setprio(0);

        // ---- P = exp2(S); inline pack + permlane into PV A-frags ----
        short8 pa[2][2];
#pragma unroll
        for (int mf = 0; mf < 2; mf++) {
#pragma unroll
            for (int kk = 0; kk < 2; kk++) {
                u32x4 wd;
#pragma unroll
                for (int b = 0; b < 2; b++) {
                    float p00 = __builtin_amdgcn_exp2f(sc[2 * kk][mf][2 * b]);
                    float p01 = __builtin_amdgcn_exp2f(sc[2 * kk][mf][2 * b + 1]);
                    float p10 = __builtin_amdgcn_exp2f(sc[2 * kk + 1][mf][2 * b]);
                    float p11 = __builtin_amdgcn_exp2f(sc[2 * kk + 1][mf][2 * b + 1]);
                    unsigned Xw = pk2(p00, p01);
                    unsigned Yw = pk2(p10, p11);
                    uint2v s1 = __builtin_amdgcn_permlane32_swap(Xw, Yw, false, false);
                    uint2v s2 = __builtin_amdgcn_permlane16_swap(s1[0], s1[1], false, false);
                    wd[b]     = s2[0];
                    wd[2 + b] = s2[1];
                }
                pa[mf][kk] = __builtin_bit_cast(short8, wd);
            }
        }

        // ---- O += P V ; lacc += P * ones (row-sum l on matrix pipe) ----
        __builtin_amdgcn_s_setprio(1);
#pragma unroll
        for (int kk = 0; kk < 2; kk++) {
            lacc[0] = __builtin_amdgcn_mfma_f32_16x16x32_bf16(pa[0][kk], ones, lacc[0], 0, 0, 0);
            lacc[1] = __builtin_amdgcn_mfma_f32_16x16x32_bf16(pa[1][kk], ones, lacc[1], 0, 0, 0);
#pragma unroll
            for (int np = 0; np < 4; np++) {
                short8 bV = *(const short8*)&vb_[(16 * np + l15) * 72 + kk * 32 + quad * 8];
                o[0][np] = __builtin_amdgcn_mfma_f32_16x16x32_bf16(pa[0][kk], bV, o[0][np], 0, 0, 0);
                o[1][np] = __builtin_amdgcn_mfma_f32_16x16x32_bf16(pa[1][kk], bV, o[1][np], 0, 0, 0);
            }
        }
        __builtin_amdgcn_s_setprio(0);
    }

    // ---- epilogue: write unnormalized partials + row-sums ----
    float* O = half ? O2 : O1;
    float* L = half ? l2 : l1;
    const size_t rowb = (size_t)bh * TT;
#pragma unroll
    for (int mf = 0; mf < 2; mf++) {
#pragma unroll
        for (int reg = 0; reg < 4; reg++) {
            int t = t0 + 32 * w + 16 * mf + quad * 4 + reg;
            if (l15 == 0) L[rowb + t] = lacc[mf][reg];
            float* orow = O + (rowb + t) * DKK;
#pragma unroll
            for (int np = 0; np < 4; np++)
                orow[16 * np + l15] = o[mf][np][reg];
        }
    }
}

// ---------------------------------------------------------------------------
// Split-S combine: Ab[b][t][h][dk] = f2bf((O1+O2) / (l1+l2)).
// grid 2048 x 256 thr; thread handles 8 consecutive dk.
// ---------------------------------------------------------------------------
__global__ __launch_bounds__(256)
void combine_norm(const float* __restrict__ O1, const float* __restrict__ O2,
                  const float* __restrict__ l1, const float* __restrict__ l2,
                  short* __restrict__ Ab)
{
    size_t g = (size_t)blockIdx.x * 256 + threadIdx.x;
    size_t i0 = g * 8;
    int bh = (int)(i0 >> 17);          // / (2048*64)
    int t  = (int)((i0 >> 6) & 2047);
    int dk = (int)(i0 & 63);
    float inv = 1.f / (l1[(size_t)bh * TT + t] + l2[(size_t)bh * TT + t]);
    f32x4 a0 = *(const f32x4*)(O1 + i0);
    f32x4 a1 = *(const f32x4*)(O1 + i0 + 4);
    f32x4 b0 = *(const f32x4*)(O2 + i0);
    f32x4 b1 = *(const f32x4*)(O2 + i0 + 4);
    short8 v;
#pragma unroll
    for (int j = 0; j < 4; j++) v[j] = f2bf((a0[j] + b0[j]) * inv);
#pragma unroll
    for (int j = 0; j < 4; j++) v[4 + j] = f2bf((a1[j] + b1[j]) * inv);
    int b = bh >> 4, h = bh & 15;
    *(short8*)(Ab + (((size_t)(b * TT + t) * HH + h) * DKK + dk)) = v;
}

// ---------------------------------------------------------------------------
extern "C" void kernel_launch(void* const* d_in, const int* in_sizes, int n_in,
                              void* d_out, int out_size, void* d_ws, size_t ws_size,
                              hipStream_t stream)
{
    const float* query = (const float*)d_in[0];
    const float* value = (const float*)d_in[1];
    const float* key   = (const float*)d_in[2];
    const float* Wq    = (const float*)d_in[3];
    const float* bq    = (const float*)d_in[4];
    const float* Wk    = (const float*)d_in[5];
    const float* bk    = (const float*)d_in[6];
    const float* Wv    = (const float*)d_in[7];
    const float* bv    = (const float*)d_in[8];
    const float* Wo    = (const float*)d_in[9];
    const float* bo    = (const float*)d_in[10];
    float* out = (float*)d_out;

    const size_t actE = (size_t)MM * DD;    // 4.19M elems
    const size_t wE   = (size_t)DD * NN;    // 1.05M elems
    short* p = (short*)d_ws;
    short* Wqt  = p; p += wE;
    short* Wkt  = p; p += wE;
    short* Wvt  = p; p += wE;
    short* Wot  = p; p += wE;
    short* Qb   = p; p += actE;
    short* Kb   = p; p += actE;
    short* Vbt  = p; p += actE;
    short* Ab   = p; p += actE;
    float* O1f  = (float*)p; p += 2 * actE;
    float* O2f  = (float*)p; p += 2 * actE;
    float* l1f  = (float*)p; p += 4 * (size_t)BB * HH * TT;  // 2 float arrays
    float* l2f  = l1f + (size_t)BB * HH * TT;

    dim3 blk(256);

    // 1. weights fp32 [K][N] -> bf16 [N][K]
    wtrans<<<dim3(16, 16, 4), blk, 0, stream>>>(Wq, Wk, Wv, Wo, Wqt, Wkt, Wvt, Wot);

    // 2. fused QKV projections from fp32 activations; V written transposed
    gemm_qkv<<<dim3(NN / 128, MM / 128, 3), blk, 0, stream>>>(
        query, key, value, Wqt, Wkt, Wvt, bq, bk, bv, Qb, Kb, Vbt);

    // 3. flash attention, split-S across z=2 -> f32 partials
    attn_mfma<<<dim3(TT / 128, BB * HH, 2), blk, 0, stream>>>(
        Qb, Kb, Vbt, O1f, O2f, l1f, l2f);

    // 4. combine + normalize -> bf16 Ab
    combine_norm<<<dim3((unsigned)(actE / 2048)), blk, 0, stream>>>(
        O1f, O2f, l1f, l2f, Ab);

    // 5. output projection -> fp32 out
    gemm_out<<<dim3(NN / 128, MM / 64), blk, 0, stream>>>(Ab, Wot, bo, out);
}

// Round 8
// 225.390 us; speedup vs baseline: 1.1246x; 1.1050x over previous
//
#include <hip/hip_runtime.h>
#include <math.h>

#define BB  2
#define TT  2048
#define SSQ 2048
#define DD  1024
#define HH  16
#define DKK 64
#define MM  (BB*TT)      // 4096 rows of activations
#define NN  (HH*DKK)     // 1024 proj width

typedef __attribute__((ext_vector_type(8))) short short8;
typedef __attribute__((ext_vector_type(4))) float f32x4;
typedef __attribute__((ext_vector_type(2))) unsigned int uint2v;
typedef __attribute__((ext_vector_type(4))) unsigned int u32x4;

__device__ __forceinline__ short f2bf(float x) {
    unsigned u = __builtin_bit_cast(unsigned, x);
    unsigned r = (u + 0x7FFFu + ((u >> 16) & 1u)) >> 16;
    return (short)r;
}

// pack two f32 into a bf16x2 word by truncation
__device__ __forceinline__ unsigned pk2(float lo, float hi) {
    return (__builtin_bit_cast(unsigned, hi) & 0xFFFF0000u) |
           (__builtin_bit_cast(unsigned, lo) >> 16);
}

__device__ __forceinline__ void glds16(const void* g, void* l) {
    __builtin_amdgcn_global_load_lds(
        (const __attribute__((address_space(1))) void*)g,
        (__attribute__((address_space(3))) void*)l, 16, 0, 0);
}

// ---------------------------------------------------------------------------
// fp32 -> bf16 elementwise (query/key/value), grid (MM*DD/2048, 3).
// Restored (round 8): reg-staged fp32 A in gemm_qkv was the round-6/7
// regression (77us, MfmaUtil 13%); bf16 A via global_load_lds is the
// proven-fast path (round 5: gemm_qkv <46.5us).
// ---------------------------------------------------------------------------
__global__ __launch_bounds__(256)
void to_bf16_acts(const float* __restrict__ a0, const float* __restrict__ a1,
                  const float* __restrict__ a2,
                  short* __restrict__ o0, short* __restrict__ o1,
                  short* __restrict__ o2)
{
    int z = blockIdx.y;
    const float* in = (z == 0) ? a0 : (z == 1) ? a1 : a2;
    short* out = (z == 0) ? o0 : (z == 1) ? o1 : o2;
    size_t i0 = ((size_t)blockIdx.x * 256 + threadIdx.x) * 8;
    f32x4 f0 = *(const f32x4*)(in + i0);
    f32x4 f1 = *(const f32x4*)(in + i0 + 4);
    short8 v;
#pragma unroll
    for (int j = 0; j < 4; j++) v[j] = f2bf(f0[j]);
#pragma unroll
    for (int j = 0; j < 4; j++) v[4 + j] = f2bf(f1[j]);
    *(short8*)(out + i0) = v;
}

// ---------------------------------------------------------------------------
// Weight transpose+convert: fp32 [K=1024][N=1024] -> bf16 [N][K].
// grid (16,16,4): z picks which weight.
// ---------------------------------------------------------------------------
__global__ __launch_bounds__(256)
void wtrans(const float* __restrict__ w0, const float* __restrict__ w1,
            const float* __restrict__ w2, const float* __restrict__ w3,
            short* __restrict__ t0, short* __restrict__ t1,
            short* __restrict__ t2, short* __restrict__ t3)
{
    __shared__ float Ls[64][65];
    int z = blockIdx.z;
    const float* in = (z == 0) ? w0 : (z == 1) ? w1 : (z == 2) ? w2 : w3;
    short* out = (z == 0) ? t0 : (z == 1) ? t1 : (z == 2) ? t2 : t3;
    const int r0 = blockIdx.y * 64, c0 = blockIdx.x * 64;
    const int t = threadIdx.x;
    const int r = t >> 2, c4 = t & 3;

    const float* src = in + (size_t)(r0 + r) * DD + c0 + c4 * 16;
#pragma unroll
    for (int i = 0; i < 4; i++) {
        f32x4 f = *(const f32x4*)(src + i * 4);
#pragma unroll
        for (int j = 0; j < 4; j++) Ls[r][c4 * 16 + i * 4 + j] = f[j];
    }
    __syncthreads();

    short8 va, vb;
#pragma unroll
    for (int j = 0; j < 8; j++) va[j] = f2bf(Ls[c4 * 16 + j][r]);
#pragma unroll
    for (int j = 0; j < 8; j++) vb[j] = f2bf(Ls[c4 * 16 + 8 + j][r]);
    short* dst = out + (size_t)(c0 + r) * DD + r0 + c4 * 16;
    *(short8*)dst = va;
    *(short8*)(dst + 8) = vb;
}

// ---------------------------------------------------------------------------
// Fused QKV projection GEMM, bf16 in, 128x128 tiles, BK=32.
// ALL staging via global_load_lds (async, off the register critical path --
// round-7 lesson: reg-staged A = 334 TF, T14 caveat). 2-phase single-barrier
// double-buffered LDS (one barrier per K-step). XCD swizzle: XCD k owns
// m-blocks [4k,4k+4) for all z,n (round 7: FETCH 202->52MB). V (z==2) uses
// swapped MFMA operands -> stores directly to Vbt[bh][dk][t] (no vtrans).
// Q scaled by 1/sqrt(dk)*log2(e) so attention uses exp2.
// ---------------------------------------------------------------------------
__global__ __launch_bounds__(256, 3)
void gemm_qkv(const short* __restrict__ Aq, const short* __restrict__ Ak,
              const short* __restrict__ Av,
              const short* __restrict__ Wqt, const short* __restrict__ Wkt,
              const short* __restrict__ Wvt,
              const float* __restrict__ bq, const float* __restrict__ bk,
              const float* __restrict__ bv,
              short* __restrict__ Qb, short* __restrict__ Kb,
              short* __restrict__ Vbt)
{
    __shared__ short As[2][128 * 32];
    __shared__ short Bs[2][128 * 32];

    // bijective XCD swizzle over 768 blocks: d%8 = XCD k; j = d/8 in [0,96):
    // m_local = j&3 (fastest), n_blk = (j>>2)&7, z = j>>5; m_blk = 4k+m_local
    const int d = blockIdx.x + 8 * blockIdx.y + 256 * blockIdx.z;
    const int kx = d & 7, j = d >> 3;
    const int z = j >> 5;
    const int n0 = ((j >> 2) & 7) * 128;
    const int m0 = (4 * kx + (j & 3)) * 128;

    const short* A  = (z == 0) ? Aq : (z == 1) ? Ak : Av;
    const short* Bt = (z == 0) ? Wqt : (z == 1) ? Wkt : Wvt;
    const float* bias = (z == 0) ? bq : (z == 1) ? bk : bv;

    const int tid = threadIdx.x;
    const int w = tid >> 6, l = tid & 63;
    const int l15 = l & 15, quad = l >> 4;
    const int wm = w >> 1, wn = w & 1;
    const int r = tid >> 2, cseg = tid & 3;

    f32x4 acc[4][4];
#pragma unroll
    for (int i = 0; i < 4; i++)
#pragma unroll
        for (int jj = 0; jj < 4; jj++) acc[i][jj] = (f32x4){0.f, 0.f, 0.f, 0.f};

    const short* gA = A + (size_t)(m0 + r) * DD + cseg * 8;
    const short* gB = Bt + (size_t)(n0 + r) * DD + cseg * 8;

    // prologue: stage K-tile 0 into buf 0 (4x global_load_lds)
    glds16(gA + 0,               &As[0][w * 512]);
    glds16(gA + (size_t)64 * DD, &As[0][2048 + w * 512]);
    glds16(gB + 0,               &Bs[0][w * 512]);
    glds16(gB + (size_t)64 * DD, &Bs[0][2048 + w * 512]);

    for (int k0 = 0; k0 < DD; k0 += 32) {
        const int cur = (k0 >> 5) & 1;
        __syncthreads();   // buf `cur` staged (vmcnt drained); buf^1 readers done
        if (k0 + 32 < DD) {
            glds16(gA + k0 + 32,                   &As[cur ^ 1][w * 512]);
            glds16(gA + (size_t)64 * DD + k0 + 32, &As[cur ^ 1][2048 + w * 512]);
            glds16(gB + k0 + 32,                   &Bs[cur ^ 1][w * 512]);
            glds16(gB + (size_t)64 * DD + k0 + 32, &Bs[cur ^ 1][2048 + w * 512]);
        }

        short8 bF[4];
#pragma unroll
        for (int ni = 0; ni < 4; ni++)
            bF[ni] = *(const short8*)&Bs[cur][(wn * 64 + ni * 16 + l15) * 32 + quad * 8];
        if (z != 2) {
#pragma unroll
            for (int mi = 0; mi < 4; mi++) {
                short8 aF = *(const short8*)&As[cur][(wm * 64 + mi * 16 + l15) * 32 + quad * 8];
#pragma unroll
                for (int ni = 0; ni < 4; ni++)
                    acc[mi][ni] = __builtin_amdgcn_mfma_f32_16x16x32_bf16(aF, bF[ni], acc[mi][ni], 0, 0, 0);
            }
        } else {
            // swapped operands: acc[ni][mi] = C^T fragment (rows = n, cols = m)
#pragma unroll
            for (int mi = 0; mi < 4; mi++) {
                short8 aF = *(const short8*)&As[cur][(wm * 64 + mi * 16 + l15) * 32 + quad * 8];
#pragma unroll
                for (int ni = 0; ni < 4; ni++)
                    acc[ni][mi] = __builtin_amdgcn_mfma_f32_16x16x32_bf16(bF[ni], aF, acc[ni][mi], 0, 0, 0);
            }
        }
    }

    if (z != 2) {
        short* dst = (z == 0) ? Qb : Kb;
        const float scale = (z == 0) ? 0.1803368801f : 1.0f;
#pragma unroll
        for (int mi = 0; mi < 4; mi++) {
#pragma unroll
            for (int reg = 0; reg < 4; reg++) {
                int m = m0 + wm * 64 + mi * 16 + quad * 4 + reg;
                int b = m >> 11, t = m & 2047;
#pragma unroll
                for (int ni = 0; ni < 4; ni++) {
                    int n = n0 + wn * 64 + ni * 16 + l15;
                    float vv = (acc[mi][ni][reg] + bias[n]) * scale;
                    int h = n >> 6, dk = n & 63;
                    dst[((size_t)(b * HH + h) * TT + t) * DKK + dk] = f2bf(vv);
                }
            }
        }
    } else {
        // acc[ni][mi]: row (quad*4+reg) = n-side, col l15 = m-side
        const int b = m0 >> 11;
        const int tl0 = (m0 & 2047) + wm * 64;
#pragma unroll
        for (int ni = 0; ni < 4; ni++) {
#pragma unroll
            for (int reg = 0; reg < 4; reg++) {
                int n = n0 + wn * 64 + ni * 16 + quad * 4 + reg;
                int h = n >> 6, dk = n & 63;
                float bb = bias[n];
                short* vrow = Vbt + ((size_t)(b * HH + h) * DKK + dk) * SSQ;
#pragma unroll
                for (int mi = 0; mi < 4; mi++) {
                    int t = tl0 + mi * 16 + l15;
                    vrow[t] = f2bf(acc[ni][mi][reg] + bb);
                }
            }
        }
    }
}

// ---------------------------------------------------------------------------
// Output projection GEMM: out[M][D] = Ab @ Wot^T + bo, fp32 out.
// 64x128 tiles, BK=64 as TWO 32-wide panels per buffer (keeps the proven
// conflict-free 64B-stride ds_read_b128 pattern AND glds16's linear-dest
// constraint; a flat 128B-stride row would be a 16-way bank conflict).
// 16 MFMA per barrier (2x round 7's 8), 16 barriers (half). LDS 48KB,
// grid 512 = 2 blocks/CU. XCD swizzle: XCD k owns m-blocks [8k,8k+8).
// ---------------------------------------------------------------------------
__global__ __launch_bounds__(256, 3)
void gemm_out(const short* __restrict__ Ab, const short* __restrict__ Wot,
              const float* __restrict__ bo, float* __restrict__ out)
{
    __shared__ short As[2][2 * 64 * 32];    // [buf][panel][row][32]
    __shared__ short Bs[2][2 * 128 * 32];   // [buf][panel][row][32]

    // bijective XCD swizzle over 512 blocks: d%8 = XCD k; j = d/8 in [0,64):
    // m_local = j&7 (fastest), n_blk = j>>3; m_blk = 8k + m_local
    const int d = blockIdx.x + 8 * blockIdx.y;
    const int kx = d & 7, j = d >> 3;
    const int m0 = (8 * kx + (j & 7)) * 64;
    const int n0 = (j >> 3) * 128;

    const int tid = threadIdx.x;
    const int w = tid >> 6, l = tid & 63;
    const int l15 = l & 15, quad = l >> 4;
    const int wm = w >> 1, wn = w & 1;

    f32x4 acc[2][4];
#pragma unroll
    for (int i = 0; i < 2; i++)
#pragma unroll
        for (int jj = 0; jj < 4; jj++) acc[i][jj] = (f32x4){0.f, 0.f, 0.f, 0.f};

    const int r = tid >> 2, cseg = tid & 3;
    const short* gA = Ab + (size_t)(m0 + r) * DD + cseg * 8;
    const short* gB = Wot + (size_t)(n0 + r) * DD + cseg * 8;

    // stage BK=64 tile at k0 into buf: A 1 call/panel (64 rows via 256 thr),
    // B 2 calls/panel (rows r and r+64)
#define STAGE_OUT(buf, k0)                                                     \
    do {                                                                       \
        glds16(gA + (k0),                        &As[buf][w * 512]);           \
        glds16(gA + (k0) + 32,                   &As[buf][2048 + w * 512]);    \
        glds16(gB + (k0),                        &Bs[buf][w * 512]);           \
        glds16(gB + (size_t)64 * DD + (k0),      &Bs[buf][2048 + w * 512]);    \
        glds16(gB + (k0) + 32,                   &Bs[buf][4096 + w * 512]);    \
        glds16(gB + (size_t)64 * DD + (k0) + 32, &Bs[buf][6144 + w * 512]);    \
    } while (0)

    STAGE_OUT(0, 0);

    for (int k0 = 0; k0 < DD; k0 += 64) {
        const int cur = (k0 >> 6) & 1;
        __syncthreads();
        if (k0 + 64 < DD) STAGE_OUT(cur ^ 1, k0 + 64);

#pragma unroll
        for (int kk = 0; kk < 2; kk++) {
            short8 bF[4];
#pragma unroll
            for (int ni = 0; ni < 4; ni++)
                bF[ni] = *(const short8*)&Bs[cur][kk * 4096 + (wn * 64 + ni * 16 + l15) * 32 + quad * 8];
#pragma unroll
            for (int mi = 0; mi < 2; mi++) {
                short8 aF = *(const short8*)&As[cur][kk * 2048 + (wm * 32 + mi * 16 + l15) * 32 + quad * 8];
#pragma unroll
                for (int ni = 0; ni < 4; ni++)
                    acc[mi][ni] = __builtin_amdgcn_mfma_f32_16x16x32_bf16(aF, bF[ni], acc[mi][ni], 0, 0, 0);
            }
        }
    }
#undef STAGE_OUT

#pragma unroll
    for (int mi = 0; mi < 2; mi++) {
#pragma unroll
        for (int reg = 0; reg < 4; reg++) {
            int m = m0 + wm * 32 + mi * 16 + quad * 4 + reg;
#pragma unroll
            for (int ni = 0; ni < 4; ni++) {
                int n = n0 + wn * 64 + ni * 16 + l15;
                out[(size_t)m * DD + n] = acc[mi][ni][reg] + bo[n];
            }
        }
    }
}

// ---------------------------------------------------------------------------
// bf16 MFMA flash attention, split-S ACROSS BLOCKS: grid (16, 32, 2), z=half
// owns s in [1024*half, 1024*half+1024). Unchanged from round 5 (proven).
// ---------------------------------------------------------------------------
__global__ __launch_bounds__(256, 4)
void attn_mfma(const short* __restrict__ Qb, const short* __restrict__ Kb,
               const short* __restrict__ Vbt,
               float* __restrict__ O1, float* __restrict__ O2,
               float* __restrict__ l1, float* __restrict__ l2)
{
    // [dbuf][{K|V}] each 64x72 shorts: K at dbo, V at dbo+4608
    __shared__ short KV[2 * 2 * 64 * 72];   // 36864 B

    const int tid = threadIdx.x;
    const int w = tid >> 6, l = tid & 63;
    const int l15 = l & 15, quad = l >> 4;

    // bijective XCD swizzle: fid -> (tile, bh); XCD k gets bh in [4k,4k+4)
    const int fid = blockIdx.y * 16 + blockIdx.x;
    const int swz = (fid & 7) * 64 + (fid >> 3);
    const int t0 = (swz & 15) * 128;
    const int bh = swz >> 4;
    const int half = blockIdx.z;
    const size_t hb = (size_t)bh * SSQ * DKK;
    const int r = tid >> 2, c4 = tid & 3;
    const int sbase = half * 1024;

    // ---- Q fragments direct from global (B-operand layout, reused 16 tiles)
    short8 qf[2][2];
#pragma unroll
    for (int mf = 0; mf < 2; mf++)
#pragma unroll
        for (int kk = 0; kk < 2; kk++)
            qf[mf][kk] = *(const short8*)(Qb + hb +
                (size_t)(t0 + 32 * w + 16 * mf + l15) * DKK + kk * 32 + quad * 8);

    // ---- prefetch K/V tile 0 of this half's s-range ----
    const short* gkb = Kb + hb + (size_t)(sbase + r) * DKK + c4 * 16;
    const short* gvb = Vbt + hb + (size_t)r * SSQ + sbase + c4 * 16;
    short8 kr0 = *(const short8*)(gkb + 0);
    short8 kr1 = *(const short8*)(gkb + 8);
    short8 vr0 = *(const short8*)(gvb + 0);
    short8 vr1 = *(const short8*)(gvb + 8);

    f32x4 o[2][4];
#pragma unroll
    for (int mf = 0; mf < 2; mf++)
#pragma unroll
        for (int j = 0; j < 4; j++) o[mf][j] = (f32x4){0.f, 0.f, 0.f, 0.f};
    f32x4 lacc[2] = {(f32x4){0.f, 0.f, 0.f, 0.f}, (f32x4){0.f, 0.f, 0.f, 0.f}};
    const short8 ones = {(short)0x3F80, (short)0x3F80, (short)0x3F80, (short)0x3F80,
                         (short)0x3F80, (short)0x3F80, (short)0x3F80, (short)0x3F80};

    short* skb = KV + r * 72 + c4 * 16;   // staging write base

    for (int s0 = 0; s0 < 1024; s0 += 64) {
        const int dbo = (s0 & 64) ? 9216 : 0;
        // write current K/V regs into buffer `dbo`
        *(short8*)(skb + dbo)          = kr0;
        *(short8*)(skb + dbo + 8)      = kr1;
        *(short8*)(skb + dbo + 4608)   = vr0;
        *(short8*)(skb + dbo + 4616)   = vr1;
        // issue next-tile global loads (covered by this tile's compute)
        if (s0 + 64 < 1024) {
            const short* gk = gkb + (size_t)(s0 + 64) * DKK;
            const short* gv = gvb + (s0 + 64);
            kr0 = *(const short8*)(gk + 0);
            kr1 = *(const short8*)(gk + 8);
            vr0 = *(const short8*)(gv + 0);
            vr1 = *(const short8*)(gv + 8);
        }
        __syncthreads();          // tile `dbo` visible; prev-buffer readers done
        const short* kb_ = KV + dbo;
        const short* vb_ = kb_ + 4608;

        // ---- S^T = K Q^T : lane holds q-row l15, s = 16np+4quad+reg ----
        f32x4 sc[4][2];
#pragma unroll
        for (int np = 0; np < 4; np++)
#pragma unroll
            for (int mf = 0; mf < 2; mf++) sc[np][mf] = (f32x4){0.f, 0.f, 0.f, 0.f};
        __builtin_amdgcn_s_setprio(1);
#pragma unroll
        for (int kk = 0; kk < 2; kk++) {
#pragma unroll
            for (int np = 0; np < 4; np++) {
                short8 aK = *(const short8*)&kb_[(16 * np + l15) * 72 + kk * 32 + quad * 8];
                sc[np][0] = __builtin_amdgcn_mfma_f32_16x16x32_bf16(aK, qf[0][kk], sc[np][0], 0, 0, 0);
                sc[np][1] = __builtin_amdgcn_mfma_f32_16x16x32_bf16(aK, qf[1][kk], sc[np][1], 0, 0, 0);
            }
        }
        __builtin_amdgcn_s_setprio(0);

        // ---- P = exp2(S); inline pack + permlane into PV A-frags ----
        short8 pa[2][2];
#pragma unroll
        for (int mf = 0; mf < 2; mf++) {
#pragma unroll
            for (int kk = 0; kk < 2; kk++) {
                u32x4 wd;
#pragma unroll
                for (int b = 0; b < 2; b++) {
                    float p00 = __builtin_amdgcn_exp2f(sc[2 * kk][mf][2 * b]);
                    float p01 = __builtin_amdgcn_exp2f(sc[2 * kk][mf][2 * b + 1]);
                    float p10 = __builtin_amdgcn_exp2f(sc[2 * kk + 1][mf][2 * b]);
                    float p11 = __builtin_amdgcn_exp2f(sc[2 * kk + 1][mf][2 * b + 1]);
                    unsigned Xw = pk2(p00, p01);
                    unsigned Yw = pk2(p10, p11);
                    uint2v s1 = __builtin_amdgcn_permlane32_swap(Xw, Yw, false, false);
                    uint2v s2 = __builtin_amdgcn_permlane16_swap(s1[0], s1[1], false, false);
                    wd[b]     = s2[0];
                    wd[2 + b] = s2[1];
                }
                pa[mf][kk] = __builtin_bit_cast(short8, wd);
            }
        }

        // ---- O += P V ; lacc += P * ones (row-sum l on matrix pipe) ----
        __builtin_amdgcn_s_setprio(1);
#pragma unroll
        for (int kk = 0; kk < 2; kk++) {
            lacc[0] = __builtin_amdgcn_mfma_f32_16x16x32_bf16(pa[0][kk], ones, lacc[0], 0, 0, 0);
            lacc[1] = __builtin_amdgcn_mfma_f32_16x16x32_bf16(pa[1][kk], ones, lacc[1], 0, 0, 0);
#pragma unroll
            for (int np = 0; np < 4; np++) {
                short8 bV = *(const short8*)&vb_[(16 * np + l15) * 72 + kk * 32 + quad * 8];
                o[0][np] = __builtin_amdgcn_mfma_f32_16x16x32_bf16(pa[0][kk], bV, o[0][np], 0, 0, 0);
                o[1][np] = __builtin_amdgcn_mfma_f32_16x16x32_bf16(pa[1][kk], bV, o[1][np], 0, 0, 0);
            }
        }
        __builtin_amdgcn_s_setprio(0);
    }

    // ---- epilogue: write unnormalized partials + row-sums ----
    float* O = half ? O2 : O1;
    float* L = half ? l2 : l1;
    const size_t rowb = (size_t)bh * TT;
#pragma unroll
    for (int mf = 0; mf < 2; mf++) {
#pragma unroll
        for (int reg = 0; reg < 4; reg++) {
            int t = t0 + 32 * w + 16 * mf + quad * 4 + reg;
            if (l15 == 0) L[rowb + t] = lacc[mf][reg];
            float* orow = O + (rowb + t) * DKK;
#pragma unroll
            for (int np = 0; np < 4; np++)
                orow[16 * np + l15] = o[mf][np][reg];
        }
    }
}

// ---------------------------------------------------------------------------
// Split-S combine: Ab[b][t][h][dk] = f2bf((O1+O2) / (l1+l2)).
// grid 2048 x 256 thr; thread handles 8 consecutive dk.
// ---------------------------------------------------------------------------
__global__ __launch_bounds__(256)
void combine_norm(const float* __restrict__ O1, const float* __restrict__ O2,
                  const float* __restrict__ l1, const float* __restrict__ l2,
                  short* __restrict__ Ab)
{
    size_t g = (size_t)blockIdx.x * 256 + threadIdx.x;
    size_t i0 = g * 8;
    int bh = (int)(i0 >> 17);          // / (2048*64)
    int t  = (int)((i0 >> 6) & 2047);
    int dk = (int)(i0 & 63);
    float inv = 1.f / (l1[(size_t)bh * TT + t] + l2[(size_t)bh * TT + t]);
    f32x4 a0 = *(const f32x4*)(O1 + i0);
    f32x4 a1 = *(const f32x4*)(O1 + i0 + 4);
    f32x4 b0 = *(const f32x4*)(O2 + i0);
    f32x4 b1 = *(const f32x4*)(O2 + i0 + 4);
    short8 v;
#pragma unroll
    for (int j = 0; j < 4; j++) v[j] = f2bf((a0[j] + b0[j]) * inv);
#pragma unroll
    for (int j = 0; j < 4; j++) v[4 + j] = f2bf((a1[j] + b1[j]) * inv);
    int b = bh >> 4, h = bh & 15;
    *(short8*)(Ab + (((size_t)(b * TT + t) * HH + h) * DKK + dk)) = v;
}

// ---------------------------------------------------------------------------
extern "C" void kernel_launch(void* const* d_in, const int* in_sizes, int n_in,
                              void* d_out, int out_size, void* d_ws, size_t ws_size,
                              hipStream_t stream)
{
    const float* query = (const float*)d_in[0];
    const float* value = (const float*)d_in[1];
    const float* key   = (const float*)d_in[2];
    const float* Wq    = (const float*)d_in[3];
    const float* bq    = (const float*)d_in[4];
    const float* Wk    = (const float*)d_in[5];
    const float* bk    = (const float*)d_in[6];
    const float* Wv    = (const float*)d_in[7];
    const float* bv    = (const float*)d_in[8];
    const float* Wo    = (const float*)d_in[9];
    const float* bo    = (const float*)d_in[10];
    float* out = (float*)d_out;

    const size_t actE = (size_t)MM * DD;    // 4.19M elems
    const size_t wE   = (size_t)DD * NN;    // 1.05M elems
    short* p = (short*)d_ws;
    short* Aq   = p; p += actE;
    short* Ak   = p; p += actE;
    short* Av   = p; p += actE;
    short* Wqt  = p; p += wE;
    short* Wkt  = p; p += wE;
    short* Wvt  = p; p += wE;
    short* Wot  = p; p += wE;
    short* Qb   = p; p += actE;
    short* Kb   = p; p += actE;
    short* Vbt  = p; p += actE;
    short* Ab   = p; p += actE;
    float* O2f  = (float*)p; p += 2 * actE;   // 16.8 MB fresh
    // O1/l1/l2 alias the Aq/Ak/Av region (dead after gemm_qkv):
    float* O1f  = (float*)Aq;                 // spans Aq+Ak = exactly actE floats
    float* l1f  = (float*)Av;
    float* l2f  = l1f + (size_t)BB * HH * TT;

    dim3 blk(256);

    // 1. activations fp32 -> bf16
    to_bf16_acts<<<dim3((unsigned)(actE / 2048), 3), blk, 0, stream>>>(
        query, key, value, Aq, Ak, Av);

    // 2. weights fp32 [K][N] -> bf16 [N][K]
    wtrans<<<dim3(16, 16, 4), blk, 0, stream>>>(Wq, Wk, Wv, Wo, Wqt, Wkt, Wvt, Wot);

    // 3. fused QKV projections (glds16-staged); V written transposed
    gemm_qkv<<<dim3(NN / 128, MM / 128, 3), blk, 0, stream>>>(
        Aq, Ak, Av, Wqt, Wkt, Wvt, bq, bk, bv, Qb, Kb, Vbt);

    // 4. flash attention, split-S across z=2 -> f32 partials
    attn_mfma<<<dim3(TT / 128, BB * HH, 2), blk, 0, stream>>>(
        Qb, Kb, Vbt, O1f, O2f, l1f, l2f);

    // 5. combine + normalize -> bf16 Ab
    combine_norm<<<dim3((unsigned)(actE / 2048)), blk, 0, stream>>>(
        O1f, O2f, l1f, l2f, Ab);

    // 6. output projection -> fp32 out
    gemm_out<<<dim3(NN / 128, MM / 64), blk, 0, stream>>>(Ab, Wot, bo, out);
}

// Round 9
// 217.165 us; speedup vs baseline: 1.1671x; 1.0379x over previous
//
#include <hip/hip_runtime.h>
#include <math.h>

#define BB  2
#define TT  2048
#define SSQ 2048
#define DD  1024
#define HH  16
#define DKK 64
#define MM  (BB*TT)      // 4096 rows of activations
#define NN  (HH*DKK)     // 1024 proj width

typedef __attribute__((ext_vector_type(8))) short short8;
typedef __attribute__((ext_vector_type(4))) float f32x4;
typedef __attribute__((ext_vector_type(2))) unsigned int uint2v;
typedef __attribute__((ext_vector_type(4))) unsigned int u32x4;

__device__ __forceinline__ short f2bf(float x) {
    unsigned u = __builtin_bit_cast(unsigned, x);
    unsigned r = (u + 0x7FFFu + ((u >> 16) & 1u)) >> 16;
    return (short)r;
}

// pack two f32 into a bf16x2 word by truncation
__device__ __forceinline__ unsigned pk2(float lo, float hi) {
    return (__builtin_bit_cast(unsigned, hi) & 0xFFFF0000u) |
           (__builtin_bit_cast(unsigned, lo) >> 16);
}

__device__ __forceinline__ void glds16(const void* g, void* l) {
    __builtin_amdgcn_global_load_lds(
        (const __attribute__((address_space(1))) void*)g,
        (__attribute__((address_space(3))) void*)l, 16, 0, 0);
}

// ---------------------------------------------------------------------------
// prep: fused input conversion. 1-D grid 7168 x 256 thr.
//  id < 6144: fp32 -> bf16 activations (z = id>>11 picks q/k/v, 2048 blocks
//             each, 2048 elems/block).
//  id >= 6144: weight transpose+convert fp32 [K][N] -> bf16 [N][K]
//             (z = (id-6144)>>8 picks Wq/Wk/Wv/Wo, 256 blocks each, 64x64
//             tile via LDS).
// Replaces two kernels (to_bf16_acts + wtrans) -> one launch.
// ---------------------------------------------------------------------------
__global__ __launch_bounds__(256)
void prep(const float* __restrict__ aq, const float* __restrict__ ak,
          const float* __restrict__ av,
          const float* __restrict__ w0, const float* __restrict__ w1,
          const float* __restrict__ w2, const float* __restrict__ w3,
          short* __restrict__ oq, short* __restrict__ ok,
          short* __restrict__ ov,
          short* __restrict__ t0, short* __restrict__ t1,
          short* __restrict__ t2, short* __restrict__ t3)
{
    __shared__ float Ls[64][65];
    const int id = blockIdx.x;
    const int tid = threadIdx.x;

    if (id < 6144) {
        const int z = id >> 11;
        const int x = id & 2047;
        const float* in = (z == 0) ? aq : (z == 1) ? ak : av;
        short* out = (z == 0) ? oq : (z == 1) ? ok : ov;
        size_t i0 = ((size_t)x * 256 + tid) * 8;
        f32x4 f0 = *(const f32x4*)(in + i0);
        f32x4 f1 = *(const f32x4*)(in + i0 + 4);
        short8 v;
#pragma unroll
        for (int j = 0; j < 4; j++) v[j] = f2bf(f0[j]);
#pragma unroll
        for (int j = 0; j < 4; j++) v[4 + j] = f2bf(f1[j]);
        *(short8*)(out + i0) = v;
    } else {
        const int wid = id - 6144;
        const int z = wid >> 8;
        const int rem = wid & 255;
        const float* in = (z == 0) ? w0 : (z == 1) ? w1 : (z == 2) ? w2 : w3;
        short* out = (z == 0) ? t0 : (z == 1) ? t1 : (z == 2) ? t2 : t3;
        const int c0 = (rem & 15) * 64, r0 = (rem >> 4) * 64;
        const int r = tid >> 2, c4 = tid & 3;

        const float* src = in + (size_t)(r0 + r) * DD + c0 + c4 * 16;
#pragma unroll
        for (int i = 0; i < 4; i++) {
            f32x4 f = *(const f32x4*)(src + i * 4);
#pragma unroll
            for (int j = 0; j < 4; j++) Ls[r][c4 * 16 + i * 4 + j] = f[j];
        }
        __syncthreads();

        short8 va, vb;
#pragma unroll
        for (int j = 0; j < 8; j++) va[j] = f2bf(Ls[c4 * 16 + j][r]);
#pragma unroll
        for (int j = 0; j < 8; j++) vb[j] = f2bf(Ls[c4 * 16 + 8 + j][r]);
        short* dst = out + (size_t)(c0 + r) * DD + r0 + c4 * 16;
        *(short8*)dst = va;
        *(short8*)(dst + 8) = vb;
    }
}

// ---------------------------------------------------------------------------
// Fused QKV projection GEMM, bf16 in, 128x128 tiles, BK=32.
// ALL staging via global_load_lds. 2-phase single-barrier double-buffered
// LDS. XCD swizzle: XCD k owns m-blocks [4k,4k+4) (round 7: FETCH
// 202->52MB). V (z==2) uses swapped MFMA operands -> stores directly to
// Vbt[bh][dk][t]. Q scaled by 1/sqrt(dk)*log2(e). Proven sub-47us round 8.
// ---------------------------------------------------------------------------
__global__ __launch_bounds__(256, 3)
void gemm_qkv(const short* __restrict__ Aq, const short* __restrict__ Ak,
              const short* __restrict__ Av,
              const short* __restrict__ Wqt, const short* __restrict__ Wkt,
              const short* __restrict__ Wvt,
              const float* __restrict__ bq, const float* __restrict__ bk,
              const float* __restrict__ bv,
              short* __restrict__ Qb, short* __restrict__ Kb,
              short* __restrict__ Vbt)
{
    __shared__ short As[2][128 * 32];
    __shared__ short Bs[2][128 * 32];

    // bijective XCD swizzle over 768 blocks: d%8 = XCD k; j = d/8 in [0,96):
    // m_local = j&3 (fastest), n_blk = (j>>2)&7, z = j>>5; m_blk = 4k+m_local
    const int d = blockIdx.x + 8 * blockIdx.y + 256 * blockIdx.z;
    const int kx = d & 7, j = d >> 3;
    const int z = j >> 5;
    const int n0 = ((j >> 2) & 7) * 128;
    const int m0 = (4 * kx + (j & 3)) * 128;

    const short* A  = (z == 0) ? Aq : (z == 1) ? Ak : Av;
    const short* Bt = (z == 0) ? Wqt : (z == 1) ? Wkt : Wvt;
    const float* bias = (z == 0) ? bq : (z == 1) ? bk : bv;

    const int tid = threadIdx.x;
    const int w = tid >> 6, l = tid & 63;
    const int l15 = l & 15, quad = l >> 4;
    const int wm = w >> 1, wn = w & 1;
    const int r = tid >> 2, cseg = tid & 3;

    f32x4 acc[4][4];
#pragma unroll
    for (int i = 0; i < 4; i++)
#pragma unroll
        for (int jj = 0; jj < 4; jj++) acc[i][jj] = (f32x4){0.f, 0.f, 0.f, 0.f};

    const short* gA = A + (size_t)(m0 + r) * DD + cseg * 8;
    const short* gB = Bt + (size_t)(n0 + r) * DD + cseg * 8;

    // prologue: stage K-tile 0 into buf 0 (4x global_load_lds)
    glds16(gA + 0,               &As[0][w * 512]);
    glds16(gA + (size_t)64 * DD, &As[0][2048 + w * 512]);
    glds16(gB + 0,               &Bs[0][w * 512]);
    glds16(gB + (size_t)64 * DD, &Bs[0][2048 + w * 512]);

    for (int k0 = 0; k0 < DD; k0 += 32) {
        const int cur = (k0 >> 5) & 1;
        __syncthreads();   // buf `cur` staged (vmcnt drained); buf^1 readers done
        if (k0 + 32 < DD) {
            glds16(gA + k0 + 32,                   &As[cur ^ 1][w * 512]);
            glds16(gA + (size_t)64 * DD + k0 + 32, &As[cur ^ 1][2048 + w * 512]);
            glds16(gB + k0 + 32,                   &Bs[cur ^ 1][w * 512]);
            glds16(gB + (size_t)64 * DD + k0 + 32, &Bs[cur ^ 1][2048 + w * 512]);
        }

        short8 bF[4];
#pragma unroll
        for (int ni = 0; ni < 4; ni++)
            bF[ni] = *(const short8*)&Bs[cur][(wn * 64 + ni * 16 + l15) * 32 + quad * 8];
        if (z != 2) {
#pragma unroll
            for (int mi = 0; mi < 4; mi++) {
                short8 aF = *(const short8*)&As[cur][(wm * 64 + mi * 16 + l15) * 32 + quad * 8];
#pragma unroll
                for (int ni = 0; ni < 4; ni++)
                    acc[mi][ni] = __builtin_amdgcn_mfma_f32_16x16x32_bf16(aF, bF[ni], acc[mi][ni], 0, 0, 0);
            }
        } else {
            // swapped operands: acc[ni][mi] = C^T fragment (rows = n, cols = m)
#pragma unroll
            for (int mi = 0; mi < 4; mi++) {
                short8 aF = *(const short8*)&As[cur][(wm * 64 + mi * 16 + l15) * 32 + quad * 8];
#pragma unroll
                for (int ni = 0; ni < 4; ni++)
                    acc[ni][mi] = __builtin_amdgcn_mfma_f32_16x16x32_bf16(bF[ni], aF, acc[ni][mi], 0, 0, 0);
            }
        }
    }

    if (z != 2) {
        short* dst = (z == 0) ? Qb : Kb;
        const float scale = (z == 0) ? 0.1803368801f : 1.0f;
#pragma unroll
        for (int mi = 0; mi < 4; mi++) {
#pragma unroll
            for (int reg = 0; reg < 4; reg++) {
                int m = m0 + wm * 64 + mi * 16 + quad * 4 + reg;
                int b = m >> 11, t = m & 2047;
#pragma unroll
                for (int ni = 0; ni < 4; ni++) {
                    int n = n0 + wn * 64 + ni * 16 + l15;
                    float vv = (acc[mi][ni][reg] + bias[n]) * scale;
                    int h = n >> 6, dk = n & 63;
                    dst[((size_t)(b * HH + h) * TT + t) * DKK + dk] = f2bf(vv);
                }
            }
        }
    } else {
        // acc[ni][mi]: row (quad*4+reg) = n-side, col l15 = m-side
        const int b = m0 >> 11;
        const int tl0 = (m0 & 2047) + wm * 64;
#pragma unroll
        for (int ni = 0; ni < 4; ni++) {
#pragma unroll
            for (int reg = 0; reg < 4; reg++) {
                int n = n0 + wn * 64 + ni * 16 + quad * 4 + reg;
                int h = n >> 6, dk = n & 63;
                float bb = bias[n];
                short* vrow = Vbt + ((size_t)(b * HH + h) * DKK + dk) * SSQ;
#pragma unroll
                for (int mi = 0; mi < 4; mi++) {
                    int t = tl0 + mi * 16 + l15;
                    vrow[t] = f2bf(acc[ni][mi][reg] + bb);
                }
            }
        }
    }
}

// ---------------------------------------------------------------------------
// Output projection GEMM: out[M][D] = Ab @ Wot^T + bo, fp32 out.
// 64x128 tiles, BK=64 as two 32-wide panels (conflict-free 64B-stride
// ds_read_b128 + glds16 linear-dest). 16 MFMA/barrier, 16 barriers.
// XCD swizzle: XCD k owns m-blocks [8k,8k+8). Proven sub-47us round 8.
// ---------------------------------------------------------------------------
__global__ __launch_bounds__(256, 3)
void gemm_out(const short* __restrict__ Ab, const short* __restrict__ Wot,
              const float* __restrict__ bo, float* __restrict__ out)
{
    __shared__ short As[2][2 * 64 * 32];    // [buf][panel][row][32]
    __shared__ short Bs[2][2 * 128 * 32];   // [buf][panel][row][32]

    const int d = blockIdx.x + 8 * blockIdx.y;
    const int kx = d & 7, j = d >> 3;
    const int m0 = (8 * kx + (j & 7)) * 64;
    const int n0 = (j >> 3) * 128;

    const int tid = threadIdx.x;
    const int w = tid >> 6, l = tid & 63;
    const int l15 = l & 15, quad = l >> 4;
    const int wm = w >> 1, wn = w & 1;

    f32x4 acc[2][4];
#pragma unroll
    for (int i = 0; i < 2; i++)
#pragma unroll
        for (int jj = 0; jj < 4; jj++) acc[i][jj] = (f32x4){0.f, 0.f, 0.f, 0.f};

    const int r = tid >> 2, cseg = tid & 3;
    const short* gA = Ab + (size_t)(m0 + r) * DD + cseg * 8;
    const short* gB = Wot + (size_t)(n0 + r) * DD + cseg * 8;

#define STAGE_OUT(buf, k0)                                                     \
    do {                                                                       \
        glds16(gA + (k0),                        &As[buf][w * 512]);           \
        glds16(gA + (k0) + 32,                   &As[buf][2048 + w * 512]);    \
        glds16(gB + (k0),                        &Bs[buf][w * 512]);           \
        glds16(gB + (size_t)64 * DD + (k0),      &Bs[buf][2048 + w * 512]);    \
        glds16(gB + (k0) + 32,                   &Bs[buf][4096 + w * 512]);    \
        glds16(gB + (size_t)64 * DD + (k0) + 32, &Bs[buf][6144 + w * 512]);    \
    } while (0)

    STAGE_OUT(0, 0);

    for (int k0 = 0; k0 < DD; k0 += 64) {
        const int cur = (k0 >> 6) & 1;
        __syncthreads();
        if (k0 + 64 < DD) STAGE_OUT(cur ^ 1, k0 + 64);

#pragma unroll
        for (int kk = 0; kk < 2; kk++) {
            short8 bF[4];
#pragma unroll
            for (int ni = 0; ni < 4; ni++)
                bF[ni] = *(const short8*)&Bs[cur][kk * 4096 + (wn * 64 + ni * 16 + l15) * 32 + quad * 8];
#pragma unroll
            for (int mi = 0; mi < 2; mi++) {
                short8 aF = *(const short8*)&As[cur][kk * 2048 + (wm * 32 + mi * 16 + l15) * 32 + quad * 8];
#pragma unroll
                for (int ni = 0; ni < 4; ni++)
                    acc[mi][ni] = __builtin_amdgcn_mfma_f32_16x16x32_bf16(aF, bF[ni], acc[mi][ni], 0, 0, 0);
            }
        }
    }
#undef STAGE_OUT

#pragma unroll
    for (int mi = 0; mi < 2; mi++) {
#pragma unroll
        for (int reg = 0; reg < 4; reg++) {
            int m = m0 + wm * 32 + mi * 16 + quad * 4 + reg;
#pragma unroll
            for (int ni = 0; ni < 4; ni++) {
                int n = n0 + wn * 64 + ni * 16 + l15;
                out[(size_t)m * DD + n] = acc[mi][ni][reg] + bo[n];
            }
        }
    }
}

// ---------------------------------------------------------------------------
// bf16 MFMA flash attention, FULL-S (round 4 loop), BT=128, 4 waves, grid
// (16,32) = 512 blocks. Split-S dropped (round-8 accounting: split attn 47
// + combine ~10us + 58MB partial traffic > full-S 52 direct write).
// Round-5 lacc MFMA row-sum kept: mfma(P, ones) puts l for q-row
// (32w+16mf+4quad+reg) into lacc[mf][reg] of EVERY lane -> epilogue needs
// ZERO shuffles and zero VALU adds in the softmax loop (round 4 had 32
// adds/tile + shuffle chain). K/V double-buffered LDS, one barrier/tile,
// permlane P-path, Q frags direct from global, XCD swizzle, setprio.
// ---------------------------------------------------------------------------
__global__ __launch_bounds__(256, 3)
void attn_mfma(const short* __restrict__ Qb, const short* __restrict__ Kb,
               const short* __restrict__ Vbt, short* __restrict__ Ab)
{
    // [dbuf][{K|V}] each 64x72 shorts: K at dbo, V at dbo+4608
    __shared__ short KV[2 * 2 * 64 * 72];   // 36864 B

    const int tid = threadIdx.x;
    const int w = tid >> 6, l = tid & 63;
    const int l15 = l & 15, quad = l >> 4;

    // bijective XCD swizzle: fid -> (tile, bh); XCD k gets bh in [4k,4k+4)
    const int fid = blockIdx.y * 16 + blockIdx.x;
    const int swz = (fid & 7) * 64 + (fid >> 3);
    const int t0 = (swz & 15) * 128;
    const int bh = swz >> 4;
    const size_t hb = (size_t)bh * SSQ * DKK;
    const int r = tid >> 2, c4 = tid & 3;

    // ---- Q fragments direct from global (B-operand layout, reused 32 tiles)
    short8 qf[2][2];
#pragma unroll
    for (int mf = 0; mf < 2; mf++)
#pragma unroll
        for (int kk = 0; kk < 2; kk++)
            qf[mf][kk] = *(const short8*)(Qb + hb +
                (size_t)(t0 + 32 * w + 16 * mf + l15) * DKK + kk * 32 + quad * 8);

    // ---- prefetch K/V tile 0 ----
    const short* gkb = Kb + hb + (size_t)r * DKK + c4 * 16;
    const short* gvb = Vbt + hb + (size_t)r * SSQ + c4 * 16;
    short8 kr0 = *(const short8*)(gkb + 0);
    short8 kr1 = *(const short8*)(gkb + 8);
    short8 vr0 = *(const short8*)(gvb + 0);
    short8 vr1 = *(const short8*)(gvb + 8);

    f32x4 o[2][4];
#pragma unroll
    for (int mf = 0; mf < 2; mf++)
#pragma unroll
        for (int j = 0; j < 4; j++) o[mf][j] = (f32x4){0.f, 0.f, 0.f, 0.f};
    f32x4 lacc[2] = {(f32x4){0.f, 0.f, 0.f, 0.f}, (f32x4){0.f, 0.f, 0.f, 0.f}};
    const short8 ones = {(short)0x3F80, (short)0x3F80, (short)0x3F80, (short)0x3F80,
                         (short)0x3F80, (short)0x3F80, (short)0x3F80, (short)0x3F80};

    short* skb = KV + r * 72 + c4 * 16;   // staging write base

    for (int s0 = 0; s0 < SSQ; s0 += 64) {
        const int dbo = (s0 & 64) ? 9216 : 0;
        // write current K/V regs into buffer `dbo`
        *(short8*)(skb + dbo)          = kr0;
        *(short8*)(skb + dbo + 8)      = kr1;
        *(short8*)(skb + dbo + 4608)   = vr0;
        *(short8*)(skb + dbo + 4616)   = vr1;
        // issue next-tile global loads (covered by this tile's compute)
        if (s0 + 64 < SSQ) {
            const short* gk = gkb + (size_t)(s0 + 64) * DKK;
            const short* gv = gvb + (s0 + 64);
            kr0 = *(const short8*)(gk + 0);
            kr1 = *(const short8*)(gk + 8);
            vr0 = *(const short8*)(gv + 0);
            vr1 = *(const short8*)(gv + 8);
        }
        __syncthreads();          // tile `dbo` visible; prev-buffer readers done
        const short* kb_ = KV + dbo;
        const short* vb_ = kb_ + 4608;

        // ---- S^T = K Q^T : lane holds q-row l15, s = 16np+4quad+reg ----
        f32x4 sc[4][2];
#pragma unroll
        for (int np = 0; np < 4; np++)
#pragma unroll
            for (int mf = 0; mf < 2; mf++) sc[np][mf] = (f32x4){0.f, 0.f, 0.f, 0.f};
        __builtin_amdgcn_s_setprio(1);
#pragma unroll
        for (int kk = 0; kk < 2; kk++) {
#pragma unroll
            for (int np = 0; np < 4; np++) {
                short8 aK = *(const short8*)&kb_[(16 * np + l15) * 72 + kk * 32 + quad * 8];
                sc[np][0] = __builtin_amdgcn_mfma_f32_16x16x32_bf16(aK, qf[0][kk], sc[np][0], 0, 0, 0);
                sc[np][1] = __builtin_amdgcn_mfma_f32_16x16x32_bf16(aK, qf[1][kk], sc[np][1], 0, 0, 0);
            }
        }
        __builtin_amdgcn_s_setprio(0);

        // ---- P = exp2(S); inline pack + permlane into PV A-frags ----
        short8 pa[2][2];
#pragma unroll
        for (int mf = 0; mf < 2; mf++) {
#pragma unroll
            for (int kk = 0; kk < 2; kk++) {
                u32x4 wd;
#pragma unroll
                for (int b = 0; b < 2; b++) {
                    float p00 = __builtin_amdgcn_exp2f(sc[2 * kk][mf][2 * b]);
                    float p01 = __builtin_amdgcn_exp2f(sc[2 * kk][mf][2 * b + 1]);
                    float p10 = __builtin_amdgcn_exp2f(sc[2 * kk + 1][mf][2 * b]);
                    float p11 = __builtin_amdgcn_exp2f(sc[2 * kk + 1][mf][2 * b + 1]);
                    unsigned Xw = pk2(p00, p01);
                    unsigned Yw = pk2(p10, p11);
                    uint2v s1 = __builtin_amdgcn_permlane32_swap(Xw, Yw, false, false);
                    uint2v s2 = __builtin_amdgcn_permlane16_swap(s1[0], s1[1], false, false);
                    wd[b]     = s2[0];
                    wd[2 + b] = s2[1];
                }
                pa[mf][kk] = __builtin_bit_cast(short8, wd);
            }
        }

        // ---- O += P V ; lacc += P * ones (row-sum l on matrix pipe) ----
        __builtin_amdgcn_s_setprio(1);
#pragma unroll
        for (int kk = 0; kk < 2; kk++) {
            lacc[0] = __builtin_amdgcn_mfma_f32_16x16x32_bf16(pa[0][kk], ones, lacc[0], 0, 0, 0);
            lacc[1] = __builtin_amdgcn_mfma_f32_16x16x32_bf16(pa[1][kk], ones, lacc[1], 0, 0, 0);
#pragma unroll
            for (int np = 0; np < 4; np++) {
                short8 bV = *(const short8*)&vb_[(16 * np + l15) * 72 + kk * 32 + quad * 8];
                o[0][np] = __builtin_amdgcn_mfma_f32_16x16x32_bf16(pa[0][kk], bV, o[0][np], 0, 0, 0);
                o[1][np] = __builtin_amdgcn_mfma_f32_16x16x32_bf16(pa[1][kk], bV, o[1][np], 0, 0, 0);
            }
        }
        __builtin_amdgcn_s_setprio(0);
    }

    // ---- epilogue: zero-shuffle normalize (lacc holds own-row l), write ----
    const int b = bh >> 4, h = bh & 15;
#pragma unroll
    for (int mf = 0; mf < 2; mf++) {
#pragma unroll
        for (int reg = 0; reg < 4; reg++) {
            float inv = 1.f / lacc[mf][reg];
            int t = t0 + 32 * w + 16 * mf + quad * 4 + reg;
#pragma unroll
            for (int np = 0; np < 4; np++) {
                Ab[((size_t)(b * TT + t) * HH + h) * DKK + 16 * np + l15] =
                    f2bf(o[mf][np][reg] * inv);
            }
        }
    }
}

// ---------------------------------------------------------------------------
extern "C" void kernel_launch(void* const* d_in, const int* in_sizes, int n_in,
                              void* d_out, int out_size, void* d_ws, size_t ws_size,
                              hipStream_t stream)
{
    const float* query = (const float*)d_in[0];
    const float* value = (const float*)d_in[1];
    const float* key   = (const float*)d_in[2];
    const float* Wq    = (const float*)d_in[3];
    const float* bq    = (const float*)d_in[4];
    const float* Wk    = (const float*)d_in[5];
    const float* bk    = (const float*)d_in[6];
    const float* Wv    = (const float*)d_in[7];
    const float* bv    = (const float*)d_in[8];
    const float* Wo    = (const float*)d_in[9];
    const float* bo    = (const float*)d_in[10];
    float* out = (float*)d_out;

    const size_t actE = (size_t)MM * DD;    // 4.19M elems
    const size_t wE   = (size_t)DD * NN;    // 1.05M elems
    short* p = (short*)d_ws;
    short* Aq   = p; p += actE;
    short* Ak   = p; p += actE;
    short* Av   = p; p += actE;
    short* Wqt  = p; p += wE;
    short* Wkt  = p; p += wE;
    short* Wvt  = p; p += wE;
    short* Wot  = p; p += wE;
    short* Qb   = p; p += actE;
    short* Kb   = p; p += actE;
    short* Vbt  = p; p += actE;
    short* Ab   = p; p += actE;

    dim3 blk(256);

    // 1. fused prep: activations fp32->bf16 + weight transpose/convert
    prep<<<dim3(7168), blk, 0, stream>>>(
        query, key, value, Wq, Wk, Wv, Wo, Aq, Ak, Av, Wqt, Wkt, Wvt, Wot);

    // 2. fused QKV projections (glds16-staged); V written transposed
    gemm_qkv<<<dim3(NN / 128, MM / 128, 3), blk, 0, stream>>>(
        Aq, Ak, Av, Wqt, Wkt, Wvt, bq, bk, bv, Qb, Kb, Vbt);

    // 3. flash attention (full-S, zero-shuffle epilogue) -> bf16 Ab
    attn_mfma<<<dim3(TT / 128, BB * HH), blk, 0, stream>>>(Qb, Kb, Vbt, Ab);

    // 4. output projection -> fp32 out
    gemm_out<<<dim3(NN / 128, MM / 64), blk, 0, stream>>>(Ab, Wot, bo, out);
}

// Round 11
// 217.136 us; speedup vs baseline: 1.1673x; 1.0001x over previous
//
#include <hip/hip_runtime.h>
#include <math.h>

#define BB  2
#define TT  2048
#define SSQ 2048
#define DD  1024
#define HH  16
#define DKK 64
#define MM  (BB*TT)      // 4096 rows of activations
#define NN  (HH*DKK)     // 1024 proj width

typedef __attribute__((ext_vector_type(8))) short short8;
typedef __attribute__((ext_vector_type(4))) float f32x4;
typedef __attribute__((ext_vector_type(2))) unsigned int uint2v;
typedef __attribute__((ext_vector_type(4))) unsigned int u32x4;

__device__ __forceinline__ short f2bf(float x) {
    unsigned u = __builtin_bit_cast(unsigned, x);
    unsigned r = (u + 0x7FFFu + ((u >> 16) & 1u)) >> 16;
    return (short)r;
}

// pack two f32 into a bf16x2 word by truncation
__device__ __forceinline__ unsigned pk2(float lo, float hi) {
    return (__builtin_bit_cast(unsigned, hi) & 0xFFFF0000u) |
           (__builtin_bit_cast(unsigned, lo) >> 16);
}

__device__ __forceinline__ void glds16(const void* g, void* l) {
    __builtin_amdgcn_global_load_lds(
        (const __attribute__((address_space(1))) void*)g,
        (__attribute__((address_space(3))) void*)l, 16, 0, 0);
}

// ---------------------------------------------------------------------------
// prep: fused input conversion. 1-D grid 7168 x 256 thr.
//  id < 6144: fp32 -> bf16 activations (z = id>>11 picks q/k/v).
//  id >= 6144: weight transpose+convert fp32 [K][N] -> bf16 [N][K].
// ---------------------------------------------------------------------------
__global__ __launch_bounds__(256)
void prep(const float* __restrict__ aq, const float* __restrict__ ak,
          const float* __restrict__ av,
          const float* __restrict__ w0, const float* __restrict__ w1,
          const float* __restrict__ w2, const float* __restrict__ w3,
          short* __restrict__ oq, short* __restrict__ ok,
          short* __restrict__ ov,
          short* __restrict__ t0, short* __restrict__ t1,
          short* __restrict__ t2, short* __restrict__ t3)
{
    __shared__ float Ls[64][65];
    const int id = blockIdx.x;
    const int tid = threadIdx.x;

    if (id < 6144) {
        const int z = id >> 11;
        const int x = id & 2047;
        const float* in = (z == 0) ? aq : (z == 1) ? ak : av;
        short* out = (z == 0) ? oq : (z == 1) ? ok : ov;
        size_t i0 = ((size_t)x * 256 + tid) * 8;
        f32x4 f0 = *(const f32x4*)(in + i0);
        f32x4 f1 = *(const f32x4*)(in + i0 + 4);
        short8 v;
#pragma unroll
        for (int j = 0; j < 4; j++) v[j] = f2bf(f0[j]);
#pragma unroll
        for (int j = 0; j < 4; j++) v[4 + j] = f2bf(f1[j]);
        *(short8*)(out + i0) = v;
    } else {
        const int wid = id - 6144;
        const int z = wid >> 8;
        const int rem = wid & 255;
        const float* in = (z == 0) ? w0 : (z == 1) ? w1 : (z == 2) ? w2 : w3;
        short* out = (z == 0) ? t0 : (z == 1) ? t1 : (z == 2) ? t2 : t3;
        const int c0 = (rem & 15) * 64, r0 = (rem >> 4) * 64;
        const int r = tid >> 2, c4 = tid & 3;

        const float* src = in + (size_t)(r0 + r) * DD + c0 + c4 * 16;
#pragma unroll
        for (int i = 0; i < 4; i++) {
            f32x4 f = *(const f32x4*)(src + i * 4);
#pragma unroll
            for (int j = 0; j < 4; j++) Ls[r][c4 * 16 + i * 4 + j] = f[j];
        }
        __syncthreads();

        short8 va, vb;
#pragma unroll
        for (int j = 0; j < 8; j++) va[j] = f2bf(Ls[c4 * 16 + j][r]);
#pragma unroll
        for (int j = 0; j < 8; j++) vb[j] = f2bf(Ls[c4 * 16 + 8 + j][r]);
        short* dst = out + (size_t)(c0 + r) * DD + r0 + c4 * 16;
        *(short8*)dst = va;
        *(short8*)(dst + 8) = vb;
    }
}

// ---------------------------------------------------------------------------
// Fused QKV projection GEMM, bf16 in, 128x128 tiles, BK=32.
// ALL staging via global_load_lds. 2-phase single-barrier double-buffered
// LDS. XCD swizzle: XCD k owns m-blocks [4k,4k+4). V (z==2) uses swapped
// MFMA operands -> stores directly to Vbt[bh][dk][t]. Q scaled by
// 1/sqrt(dk)*log2(e). Proven ~48us round 8/9 — FROZEN.
// ---------------------------------------------------------------------------
__global__ __launch_bounds__(256, 3)
void gemm_qkv(const short* __restrict__ Aq, const short* __restrict__ Ak,
              const short* __restrict__ Av,
              const short* __restrict__ Wqt, const short* __restrict__ Wkt,
              const short* __restrict__ Wvt,
              const float* __restrict__ bq, const float* __restrict__ bk,
              const float* __restrict__ bv,
              short* __restrict__ Qb, short* __restrict__ Kb,
              short* __restrict__ Vbt)
{
    __shared__ short As[2][128 * 32];
    __shared__ short Bs[2][128 * 32];

    // bijective XCD swizzle over 768 blocks: d%8 = XCD k; j = d/8 in [0,96):
    // m_local = j&3 (fastest), n_blk = (j>>2)&7, z = j>>5; m_blk = 4k+m_local
    const int d = blockIdx.x + 8 * blockIdx.y + 256 * blockIdx.z;
    const int kx = d & 7, j = d >> 3;
    const int z = j >> 5;
    const int n0 = ((j >> 2) & 7) * 128;
    const int m0 = (4 * kx + (j & 3)) * 128;

    const short* A  = (z == 0) ? Aq : (z == 1) ? Ak : Av;
    const short* Bt = (z == 0) ? Wqt : (z == 1) ? Wkt : Wvt;
    const float* bias = (z == 0) ? bq : (z == 1) ? bk : bv;

    const int tid = threadIdx.x;
    const int w = tid >> 6, l = tid & 63;
    const int l15 = l & 15, quad = l >> 4;
    const int wm = w >> 1, wn = w & 1;
    const int r = tid >> 2, cseg = tid & 3;

    f32x4 acc[4][4];
#pragma unroll
    for (int i = 0; i < 4; i++)
#pragma unroll
        for (int jj = 0; jj < 4; jj++) acc[i][jj] = (f32x4){0.f, 0.f, 0.f, 0.f};

    const short* gA = A + (size_t)(m0 + r) * DD + cseg * 8;
    const short* gB = Bt + (size_t)(n0 + r) * DD + cseg * 8;

    // prologue: stage K-tile 0 into buf 0 (4x global_load_lds)
    glds16(gA + 0,               &As[0][w * 512]);
    glds16(gA + (size_t)64 * DD, &As[0][2048 + w * 512]);
    glds16(gB + 0,               &Bs[0][w * 512]);
    glds16(gB + (size_t)64 * DD, &Bs[0][2048 + w * 512]);

    for (int k0 = 0; k0 < DD; k0 += 32) {
        const int cur = (k0 >> 5) & 1;
        __syncthreads();   // buf `cur` staged (vmcnt drained); buf^1 readers done
        if (k0 + 32 < DD) {
            glds16(gA + k0 + 32,                   &As[cur ^ 1][w * 512]);
            glds16(gA + (size_t)64 * DD + k0 + 32, &As[cur ^ 1][2048 + w * 512]);
            glds16(gB + k0 + 32,                   &Bs[cur ^ 1][w * 512]);
            glds16(gB + (size_t)64 * DD + k0 + 32, &Bs[cur ^ 1][2048 + w * 512]);
        }

        short8 bF[4];
#pragma unroll
        for (int ni = 0; ni < 4; ni++)
            bF[ni] = *(const short8*)&Bs[cur][(wn * 64 + ni * 16 + l15) * 32 + quad * 8];
        if (z != 2) {
#pragma unroll
            for (int mi = 0; mi < 4; mi++) {
                short8 aF = *(const short8*)&As[cur][(wm * 64 + mi * 16 + l15) * 32 + quad * 8];
#pragma unroll
                for (int ni = 0; ni < 4; ni++)
                    acc[mi][ni] = __builtin_amdgcn_mfma_f32_16x16x32_bf16(aF, bF[ni], acc[mi][ni], 0, 0, 0);
            }
        } else {
            // swapped operands: acc[ni][mi] = C^T fragment (rows = n, cols = m)
#pragma unroll
            for (int mi = 0; mi < 4; mi++) {
                short8 aF = *(const short8*)&As[cur][(wm * 64 + mi * 16 + l15) * 32 + quad * 8];
#pragma unroll
                for (int ni = 0; ni < 4; ni++)
                    acc[ni][mi] = __builtin_amdgcn_mfma_f32_16x16x32_bf16(bF[ni], aF, acc[ni][mi], 0, 0, 0);
            }
        }
    }

    if (z != 2) {
        short* dst = (z == 0) ? Qb : Kb;
        const float scale = (z == 0) ? 0.1803368801f : 1.0f;
#pragma unroll
        for (int mi = 0; mi < 4; mi++) {
#pragma unroll
            for (int reg = 0; reg < 4; reg++) {
                int m = m0 + wm * 64 + mi * 16 + quad * 4 + reg;
                int b = m >> 11, t = m & 2047;
#pragma unroll
                for (int ni = 0; ni < 4; ni++) {
                    int n = n0 + wn * 64 + ni * 16 + l15;
                    float vv = (acc[mi][ni][reg] + bias[n]) * scale;
                    int h = n >> 6, dk = n & 63;
                    dst[((size_t)(b * HH + h) * TT + t) * DKK + dk] = f2bf(vv);
                }
            }
        }
    } else {
        // acc[ni][mi]: row (quad*4+reg) = n-side, col l15 = m-side
        const int b = m0 >> 11;
        const int tl0 = (m0 & 2047) + wm * 64;
#pragma unroll
        for (int ni = 0; ni < 4; ni++) {
#pragma unroll
            for (int reg = 0; reg < 4; reg++) {
                int n = n0 + wn * 64 + ni * 16 + quad * 4 + reg;
                int h = n >> 6, dk = n & 63;
                float bb = bias[n];
                short* vrow = Vbt + ((size_t)(b * HH + h) * DKK + dk) * SSQ;
#pragma unroll
                for (int mi = 0; mi < 4; mi++) {
                    int t = tl0 + mi * 16 + l15;
                    vrow[t] = f2bf(acc[ni][mi][reg] + bb);
                }
            }
        }
    }
}

// ---------------------------------------------------------------------------
// Output projection GEMM: out[M][D] = Ab @ Wot^T + bo, fp32 out.
// 64x64 tiles, BK=64 (two 32-col panels/buffer), grid 1024 = 4 blocks/CU
// (was 2/CU grid-capped, the ~200TF laggard by cross-round accounting).
// 16 waves/CU doubles latency cover; per-wave 32x32 output (2x2 frags),
// 8 MFMA + 8 ds_read/K-step. Two-panel [kk][row][32] layout keeps 64B row
// stride (conflict-free ds_read_b128) + glds16 linear dest. LDS 32KB.
// XCD swizzle: XCD k owns m-blocks [8k,8k+8) -> A 1MB + B 2MB per XCD.
// ---------------------------------------------------------------------------
__global__ __launch_bounds__(256, 4)
void gemm_out(const short* __restrict__ Ab, const short* __restrict__ Wot,
              const float* __restrict__ bo, float* __restrict__ out)
{
    __shared__ short As[2][2 * 64 * 32];   // [buf][panel][row][32]
    __shared__ short Bs[2][2 * 64 * 32];   // [buf][panel][row][32]

    // bijective XCD swizzle over 1024 blocks: d%8 = XCD k; j = d/8 in [0,128):
    // m_local = j&7 (fastest), n_blk = j>>3; m_blk = 8k + m_local
    const int d = blockIdx.x;
    const int kx = d & 7, j = d >> 3;
    const int m0 = (8 * kx + (j & 7)) * 64;
    const int n0 = (j >> 3) * 64;

    const int tid = threadIdx.x;
    const int w = tid >> 6, l = tid & 63;
    const int l15 = l & 15, quad = l >> 4;
    const int wm = w >> 1, wn = w & 1;

    f32x4 acc[2][2];
#pragma unroll
    for (int i = 0; i < 2; i++)
#pragma unroll
        for (int jj = 0; jj < 2; jj++) acc[i][jj] = (f32x4){0.f, 0.f, 0.f, 0.f};

    const int r = tid >> 2, cseg = tid & 3;
    const short* gA = Ab + (size_t)(m0 + r) * DD + cseg * 8;
    const short* gB = Wot + (size_t)(n0 + r) * DD + cseg * 8;

    // stage BK=64 tile at k0 into buf: 1 glds16 per panel per operand
#define STAGE_OUT(buf, k0)                                        \
    do {                                                          \
        glds16(gA + (k0),      &As[buf][w * 512]);                \
        glds16(gA + (k0) + 32, &As[buf][2048 + w * 512]);         \
        glds16(gB + (k0),      &Bs[buf][w * 512]);                \
        glds16(gB + (k0) + 32, &Bs[buf][2048 + w * 512]);         \
    } while (0)

    STAGE_OUT(0, 0);

    for (int k0 = 0; k0 < DD; k0 += 64) {
        const int cur = (k0 >> 6) & 1;
        __syncthreads();
        if (k0 + 64 < DD) STAGE_OUT(cur ^ 1, k0 + 64);

#pragma unroll
        for (int kk = 0; kk < 2; kk++) {
            short8 bF[2];
#pragma unroll
            for (int ni = 0; ni < 2; ni++)
                bF[ni] = *(const short8*)&Bs[cur][kk * 2048 + (wn * 32 + ni * 16 + l15) * 32 + quad * 8];
#pragma unroll
            for (int mi = 0; mi < 2; mi++) {
                short8 aF = *(const short8*)&As[cur][kk * 2048 + (wm * 32 + mi * 16 + l15) * 32 + quad * 8];
#pragma unroll
                for (int ni = 0; ni < 2; ni++)
                    acc[mi][ni] = __builtin_amdgcn_mfma_f32_16x16x32_bf16(aF, bF[ni], acc[mi][ni], 0, 0, 0);
            }
        }
    }
#undef STAGE_OUT

#pragma unroll
    for (int mi = 0; mi < 2; mi++) {
#pragma unroll
        for (int reg = 0; reg < 4; reg++) {
            int m = m0 + wm * 32 + mi * 16 + quad * 4 + reg;
#pragma unroll
            for (int ni = 0; ni < 2; ni++) {
                int n = n0 + wn * 32 + ni * 16 + l15;
                out[(size_t)m * DD + n] = acc[mi][ni][reg] + bo[n];
            }
        }
    }
}

// ---------------------------------------------------------------------------
// bf16 MFMA flash attention, FULL-S, BT=128, 4 waves, grid (16,32) = 512.
// lacc MFMA row-sum -> zero-shuffle epilogue. K/V double-buffered LDS, one
// barrier/tile, permlane P-path, Q frags direct from global, XCD swizzle,
// setprio. Proven 48.9us round 9 — FROZEN.
// ---------------------------------------------------------------------------
__global__ __launch_bounds__(256, 3)
void attn_mfma(const short* __restrict__ Qb, const short* __restrict__ Kb,
               const short* __restrict__ Vbt, short* __restrict__ Ab)
{
    // [dbuf][{K|V}] each 64x72 shorts: K at dbo, V at dbo+4608
    __shared__ short KV[2 * 2 * 64 * 72];   // 36864 B

    const int tid = threadIdx.x;
    const int w = tid >> 6, l = tid & 63;
    const int l15 = l & 15, quad = l >> 4;

    // bijective XCD swizzle: fid -> (tile, bh); XCD k gets bh in [4k,4k+4)
    const int fid = blockIdx.y * 16 + blockIdx.x;
    const int swz = (fid & 7) * 64 + (fid >> 3);
    const int t0 = (swz & 15) * 128;
    const int bh = swz >> 4;
    const size_t hb = (size_t)bh * SSQ * DKK;
    const int r = tid >> 2, c4 = tid & 3;

    // ---- Q fragments direct from global (B-operand layout, reused 32 tiles)
    short8 qf[2][2];
#pragma unroll
    for (int mf = 0; mf < 2; mf++)
#pragma unroll
        for (int kk = 0; kk < 2; kk++)
            qf[mf][kk] = *(const short8*)(Qb + hb +
                (size_t)(t0 + 32 * w + 16 * mf + l15) * DKK + kk * 32 + quad * 8);

    // ---- prefetch K/V tile 0 ----
    const short* gkb = Kb + hb + (size_t)r * DKK + c4 * 16;
    const short* gvb = Vbt + hb + (size_t)r * SSQ + c4 * 16;
    short8 kr0 = *(const short8*)(gkb + 0);
    short8 kr1 = *(const short8*)(gkb + 8);
    short8 vr0 = *(const short8*)(gvb + 0);
    short8 vr1 = *(const short8*)(gvb + 8);

    f32x4 o[2][4];
#pragma unroll
    for (int mf = 0; mf < 2; mf++)
#pragma unroll
        for (int j = 0; j < 4; j++) o[mf][j] = (f32x4){0.f, 0.f, 0.f, 0.f};
    f32x4 lacc[2] = {(f32x4){0.f, 0.f, 0.f, 0.f}, (f32x4){0.f, 0.f, 0.f, 0.f}};
    const short8 ones = {(short)0x3F80, (short)0x3F80, (short)0x3F80, (short)0x3F80,
                         (short)0x3F80, (short)0x3F80, (short)0x3F80, (short)0x3F80};

    short* skb = KV + r * 72 + c4 * 16;   // staging write base

    for (int s0 = 0; s0 < SSQ; s0 += 64) {
        const int dbo = (s0 & 64) ? 9216 : 0;
        // write current K/V regs into buffer `dbo`
        *(short8*)(skb + dbo)          = kr0;
        *(short8*)(skb + dbo + 8)      = kr1;
        *(short8*)(skb + dbo + 4608)   = vr0;
        *(short8*)(skb + dbo + 4616)   = vr1;
        // issue next-tile global loads (covered by this tile's compute)
        if (s0 + 64 < SSQ) {
            const short* gk = gkb + (size_t)(s0 + 64) * DKK;
            const short* gv = gvb + (s0 + 64);
            kr0 = *(const short8*)(gk + 0);
            kr1 = *(const short8*)(gk + 8);
            vr0 = *(const short8*)(gv + 0);
            vr1 = *(const short8*)(gv + 8);
        }
        __syncthreads();          // tile `dbo` visible; prev-buffer readers done
        const short* kb_ = KV + dbo;
        const short* vb_ = kb_ + 4608;

        // ---- S^T = K Q^T : lane holds q-row l15, s = 16np+4quad+reg ----
        f32x4 sc[4][2];
#pragma unroll
        for (int np = 0; np < 4; np++)
#pragma unroll
            for (int mf = 0; mf < 2; mf++) sc[np][mf] = (f32x4){0.f, 0.f, 0.f, 0.f};
        __builtin_amdgcn_s_setprio(1);
#pragma unroll
        for (int kk = 0; kk < 2; kk++) {
#pragma unroll
            for (int np = 0; np < 4; np++) {
                short8 aK = *(const short8*)&kb_[(16 * np + l15) * 72 + kk * 32 + quad * 8];
                sc[np][0] = __builtin_amdgcn_mfma_f32_16x16x32_bf16(aK, qf[0][kk], sc[np][0], 0, 0, 0);
                sc[np][1] = __builtin_amdgcn_mfma_f32_16x16x32_bf16(aK, qf[1][kk], sc[np][1], 0, 0, 0);
            }
        }
        __builtin_amdgcn_s_setprio(0);

        // ---- P = exp2(S); inline pack + permlane into PV A-frags ----
        short8 pa[2][2];
#pragma unroll
        for (int mf = 0; mf < 2; mf++) {
#pragma unroll
            for (int kk = 0; kk < 2; kk++) {
                u32x4 wd;
#pragma unroll
                for (int b = 0; b < 2; b++) {
                    float p00 = __builtin_amdgcn_exp2f(sc[2 * kk][mf][2 * b]);
                    float p01 = __builtin_amdgcn_exp2f(sc[2 * kk][mf][2 * b + 1]);
                    float p10 = __builtin_amdgcn_exp2f(sc[2 * kk + 1][mf][2 * b]);
                    float p11 = __builtin_amdgcn_exp2f(sc[2 * kk + 1][mf][2 * b + 1]);
                    unsigned Xw = pk2(p00, p01);
                    unsigned Yw = pk2(p10, p11);
                    uint2v s1 = __builtin_amdgcn_permlane32_swap(Xw, Yw, false, false);
                    uint2v s2 = __builtin_amdgcn_permlane16_swap(s1[0], s1[1], false, false);
                    wd[b]     = s2[0];
                    wd[2 + b] = s2[1];
                }
                pa[mf][kk] = __builtin_bit_cast(short8, wd);
            }
        }

        // ---- O += P V ; lacc += P * ones (row-sum l on matrix pipe) ----
        __builtin_amdgcn_s_setprio(1);
#pragma unroll
        for (int kk = 0; kk < 2; kk++) {
            lacc[0] = __builtin_amdgcn_mfma_f32_16x16x32_bf16(pa[0][kk], ones, lacc[0], 0, 0, 0);
            lacc[1] = __builtin_amdgcn_mfma_f32_16x16x32_bf16(pa[1][kk], ones, lacc[1], 0, 0, 0);
#pragma unroll
            for (int np = 0; np < 4; np++) {
                short8 bV = *(const short8*)&vb_[(16 * np + l15) * 72 + kk * 32 + quad * 8];
                o[0][np] = __builtin_amdgcn_mfma_f32_16x16x32_bf16(pa[0][kk], bV, o[0][np], 0, 0, 0);
                o[1][np] = __builtin_amdgcn_mfma_f32_16x16x32_bf16(pa[1][kk], bV, o[1][np], 0, 0, 0);
            }
        }
        __builtin_amdgcn_s_setprio(0);
    }

    // ---- epilogue: zero-shuffle normalize (lacc holds own-row l), write ----
    const int b = bh >> 4, h = bh & 15;
#pragma unroll
    for (int mf = 0; mf < 2; mf++) {
#pragma unroll
        for (int reg = 0; reg < 4; reg++) {
            float inv = 1.f / lacc[mf][reg];
            int t = t0 + 32 * w + 16 * mf + quad * 4 + reg;
#pragma unroll
            for (int np = 0; np < 4; np++) {
                Ab[((size_t)(b * TT + t) * HH + h) * DKK + 16 * np + l15] =
                    f2bf(o[mf][np][reg] * inv);
            }
        }
    }
}

// ---------------------------------------------------------------------------
extern "C" void kernel_launch(void* const* d_in, const int* in_sizes, int n_in,
                              void* d_out, int out_size, void* d_ws, size_t ws_size,
                              hipStream_t stream)
{
    const float* query = (const float*)d_in[0];
    const float* value = (const float*)d_in[1];
    const float* key   = (const float*)d_in[2];
    const float* Wq    = (const float*)d_in[3];
    const float* bq    = (const float*)d_in[4];
    const float* Wk    = (const float*)d_in[5];
    const float* bk    = (const float*)d_in[6];
    const float* Wv    = (const float*)d_in[7];
    const float* bv    = (const float*)d_in[8];
    const float* Wo    = (const float*)d_in[9];
    const float* bo    = (const float*)d_in[10];
    float* out = (float*)d_out;

    const size_t actE = (size_t)MM * DD;    // 4.19M elems
    const size_t wE   = (size_t)DD * NN;    // 1.05M elems
    short* p = (short*)d_ws;
    short* Aq   = p; p += actE;
    short* Ak   = p; p += actE;
    short* Av   = p; p += actE;
    short* Wqt  = p; p += wE;
    short* Wkt  = p; p += wE;
    short* Wvt  = p; p += wE;
    short* Wot  = p; p += wE;
    short* Qb   = p; p += actE;
    short* Kb   = p; p += actE;
    short* Vbt  = p; p += actE;
    short* Ab   = p; p += actE;

    dim3 blk(256);

    // 1. fused prep: activations fp32->bf16 + weight transpose/convert
    prep<<<dim3(7168), blk, 0, stream>>>(
        query, key, value, Wq, Wk, Wv, Wo, Aq, Ak, Av, Wqt, Wkt, Wvt, Wot);

    // 2. fused QKV projections (glds16-staged); V written transposed
    gemm_qkv<<<dim3(NN / 128, MM / 128, 3), blk, 0, stream>>>(
        Aq, Ak, Av, Wqt, Wkt, Wvt, bq, bk, bv, Qb, Kb, Vbt);

    // 3. flash attention (full-S, zero-shuffle epilogue) -> bf16 Ab
    attn_mfma<<<dim3(TT / 128, BB * HH), blk, 0, stream>>>(Qb, Kb, Vbt, Ab);

    // 4. output projection (64x64 tiles, 4 blocks/CU) -> fp32 out
    gemm_out<<<dim3(1024), blk, 0, stream>>>(Ab, Wot, bo, out);
}